// Round 4
// baseline (1008.469 us; speedup 1.0000x reference)
//
#include <hip/hip_runtime.h>

#define DIM 64
#define NG 8
#define SCAN_B 1024
#define EPT 8      // edges per thread in hist/bin kernels (tile = 256*EPT = 2048)
#define FB_LOG 13
#define FB 8192    // fine-bucket size: 8192 col slots = 32 KB
#define MAXNF 384  // max fine buckets per coarse bucket (ceil(3e6/8192)=367)

typedef unsigned int uint;
typedef unsigned short ushort;

// ---- bf16 helpers ----
__device__ __forceinline__ float bf16_lo(uint u) {
    union { uint u; float f; } c; c.u = u << 16; return c.f;
}
__device__ __forceinline__ float bf16_hi(uint u) {
    union { uint u; float f; } c; c.u = u & 0xffff0000u; return c.f;
}
__device__ __forceinline__ uint f2b(float f) {   // bf16 in low 16 bits (RNE)
    union { float f; uint u; } c; c.f = f;
    return (c.u + 0x7fffu + ((c.u >> 16) & 1u)) >> 16;
}

// f32 -> bf16, 8 elems/thread, output row pitch/offset in ushorts (rows of 64).
__global__ void cvt_bf16_pitch(const float* __restrict__ in, ushort* __restrict__ out,
                               int n8, int pitch, int off) {
    int k = blockIdx.x * blockDim.x + threadIdx.x;
    if (k >= n8) return;
    int row = k >> 3, g = k & 7;
    const float4* p = (const float4*)in + (size_t)k * 2;
    float4 a = p[0], b = p[1];
    uint4 o;
    o.x = f2b(a.x) | (f2b(a.y) << 16);
    o.y = f2b(a.z) | (f2b(a.w) << 16);
    o.z = f2b(b.x) | (f2b(b.y) << 16);
    o.w = f2b(b.z) | (f2b(b.w) << 16);
    *(uint4*)(out + (size_t)row * pitch + off + g * 8) = o;
}

// ---- CSR build ----
// Per-node degree histogram + per-group (16-bucket) edge counts.
__global__ __launch_bounds__(256) void edge_hist(
        const int* __restrict__ src, const int* __restrict__ dst,
        int* __restrict__ deg, int* __restrict__ gcnt,
        int n_users, int E, int uchunk, int ichunk) {
    __shared__ int h[16];
    if (threadIdx.x < 16) h[threadIdx.x] = 0;
    __syncthreads();
    int t0 = blockIdx.x * (256 * EPT) + threadIdx.x;
    #pragma unroll
    for (int k = 0; k < EPT; ++k) {
        int e = t0 + k * 256;
        if (e < E) {
            int s = src[e], t = dst[e];
            atomicAdd(&deg[s], 1);
            atomicAdd(&deg[n_users + t], 1);
            atomicAdd(&h[s / uchunk], 1);
            atomicAdd(&h[8 + t / ichunk], 1);
        }
    }
    __syncthreads();
    if (threadIdx.x < 16) {
        int v = h[threadIdx.x];
        if (v) atomicAdd(&gcnt[threadIdx.x], v);
    }
}

// Exclusive scan of the 16 bucket counts -> bucket bases (col space == bins
// space), fine-bucket bases (fstart), and cursor2[f] = f*FB (bins2 slots).
__global__ void scan16(const int* __restrict__ gcnt, int* __restrict__ cursor,
                       int* __restrict__ bstart, int* __restrict__ fstart,
                       int* __restrict__ cursor2) {
    if (threadIdx.x == 0) {
        int run = 0, frun = 0;
        for (int b = 0; b < 16; ++b) {
            bstart[b] = run;
            cursor[b] = run;
            fstart[b] = frun;
            run  += gcnt[b];
            frun += (gcnt[b] + FB - 1) >> FB_LOG;
        }
        bstart[16] = run;    // == 2E
        fstart[16] = frun;   // total fine buckets
    }
    __syncthreads();
    int nf = fstart[16];
    for (int f = threadIdx.x; f < nf; f += blockDim.x)
        cursor2[f] = f << FB_LOG;
}

// Phase 1: single read of the edge list; scatter each edge into its user-group
// bucket and item-group bucket as ONE packed u32.
//   user word: s_local | (t << 15)   (uchunk=25000 < 2^15, t < 2^17)
//   item word: t_local | (s << 14)   (ichunk=12500 < 2^14, s < 2^18)
// LDS per-tile counters + one global cursor atomicAdd per bucket per tile make
// the bucket writes dense ~1KB chunks (no write amplification).
__global__ __launch_bounds__(256) void bin_edges(
        const int* __restrict__ src, const int* __restrict__ dst,
        int* __restrict__ cursor, uint* __restrict__ bins,
        int E, int uchunk, int ichunk) {
    __shared__ int cnt[16];
    __shared__ int base[16];
    if (threadIdx.x < 16) cnt[threadIdx.x] = 0;
    __syncthreads();
    int t0 = blockIdx.x * (256 * EPT) + threadIdx.x;
    int s[EPT], t[EPT], bu[EPT], bi[EPT], ou[EPT], oi[EPT];
    #pragma unroll
    for (int k = 0; k < EPT; ++k) {
        int e = t0 + k * 256;
        if (e < E) {
            s[k] = src[e]; t[k] = dst[e];
            bu[k] = s[k] / uchunk;
            bi[k] = t[k] / ichunk;
            ou[k] = atomicAdd(&cnt[bu[k]], 1);
            oi[k] = atomicAdd(&cnt[8 + bi[k]], 1);
        }
    }
    __syncthreads();
    if (threadIdx.x < 16)
        base[threadIdx.x] = atomicAdd(&cursor[threadIdx.x], cnt[threadIdx.x]);
    __syncthreads();
    #pragma unroll
    for (int k = 0; k < EPT; ++k) {
        int e = t0 + k * 256;
        if (e < E) {
            uint wu = (uint)(s[k] - bu[k] * uchunk) | ((uint)t[k] << 15);
            uint wi = (uint)(t[k] - bi[k] * ichunk) | ((uint)s[k] << 14);
            __builtin_nontemporal_store(wu, &bins[base[bu[k]] + ou[k]]);
            __builtin_nontemporal_store(wi, &bins[base[8 + bi[k]] + oi[k]]);
        }
    }
}

// Phase 2: per coarse bucket, assign each entry its exact col slot via the deg
// cursor atomic, then re-bin by 8192-slot fine bucket (col window) as
//   word = (pos & 8191) | (neighbor << 13)    (13+18 = 31 bits max)
// LDS per-tile counts over <=367 fine buckets + cursor2 chunk atomics give
// ~360B dense runs into bins2 — the scatter never reaches HBM at 4B granule.
__global__ __launch_bounds__(256) void bin_fine(
        const uint* __restrict__ bins, const int* __restrict__ bstart,
        const int* __restrict__ fstart, int* __restrict__ deg,
        int* __restrict__ cursor2, uint* __restrict__ bins2,
        int n_users, int uchunk, int ichunk) {
    __shared__ int cnt[MAXNF];
    __shared__ int base[MAXNF];
    const int b   = blockIdx.x & 15;
    const int bi  = blockIdx.x >> 4;
    const int bpb = gridDim.x >> 4;
    const int lo = bstart[b], hi = bstart[b + 1];
    if (lo >= hi) return;
    const int nf  = (hi - lo + FB - 1) >> FB_LOG;
    const int fb0 = fstart[b];
    const int nodebase = (b < 8) ? b * uchunk : n_users + (b - 8) * ichunk;
    const uint lmask  = (b < 8) ? 32767u : 16383u;
    const int  lshift = (b < 8) ? 15 : 14;
    const int TILE = 4096;
    const int ntiles = (hi - lo + TILE - 1) / TILE;
    for (int tile = bi; tile < ntiles; tile += bpb) {
        const int tbeg = lo + tile * TILE;
        const int tend = min(tbeg + TILE, hi);
        for (int j = threadIdx.x; j < nf; j += 256) cnt[j] = 0;
        __syncthreads();
        uint w[16]; int kf[16]; int off[16];
        #pragma unroll
        for (int k = 0; k < 16; ++k) {
            int idx = tbeg + k * 256 + threadIdx.x;
            kf[k] = -1;
            if (idx < tend) {
                uint ww = __builtin_nontemporal_load(&bins[idx]);
                int node = nodebase + (int)(ww & lmask);
                uint nbr = ww >> lshift;
                int pos = atomicAdd(&deg[node], 1);
                int rel = pos - lo;
                kf[k]  = rel >> FB_LOG;
                w[k]   = (uint)(rel & (FB - 1)) | (nbr << FB_LOG);
                off[k] = atomicAdd(&cnt[kf[k]], 1);
            }
        }
        __syncthreads();
        for (int j = threadIdx.x; j < nf; j += 256) {
            int c = cnt[j];
            if (c) base[j] = atomicAdd(&cursor2[fb0 + j], c);
        }
        __syncthreads();
        #pragma unroll
        for (int k = 0; k < 16; ++k)
            if (kf[k] >= 0)
                __builtin_nontemporal_store(w[k], &bins2[(size_t)(base[kf[k]] + off[k])]);
    }
}

// Phase 3: one block per fine bucket. Dense read of its 8192 packed entries,
// collision-free LDS scatter by the carried 13-bit local slot, then ONE dense
// 32 KB write to col — full lines only, zero write amplification. Plain
// (cached) loads/stores: col is re-read by the gathers right after and fits L3.
__global__ __launch_bounds__(256) void fill_fine(
        const uint* __restrict__ bins2, const int* __restrict__ bstart,
        const int* __restrict__ fstart, int* __restrict__ col) {
    __shared__ int buf[FB];
    const int f = blockIdx.x;
    if (f >= fstart[16]) return;
    int b = 0;
    #pragma unroll
    for (int j = 1; j < 16; ++j) if (fstart[j] <= f) b = j;
    const int k = f - fstart[b];
    const int cstart = bstart[b] + (k << FB_LOG);
    const int count = min(FB, bstart[b + 1] - cstart);
    const uint* in = bins2 + (size_t)f * FB;
    if (count == FB) {
        #pragma unroll
        for (int q = 0; q < 8; ++q) {
            uint4 v = *((const uint4*)in + q * 256 + threadIdx.x);
            buf[v.x & (FB - 1)] = (int)(v.x >> FB_LOG);
            buf[v.y & (FB - 1)] = (int)(v.y >> FB_LOG);
            buf[v.z & (FB - 1)] = (int)(v.z >> FB_LOG);
            buf[v.w & (FB - 1)] = (int)(v.w >> FB_LOG);
        }
        __syncthreads();
        #pragma unroll
        for (int q = 0; q < 8; ++q) {
            int j = (q * 256 + threadIdx.x) * 4;
            int4 o; o.x = buf[j]; o.y = buf[j + 1]; o.z = buf[j + 2]; o.w = buf[j + 3];
            *(int4*)(col + cstart + j) = o;
        }
    } else {
        for (int j = threadIdx.x; j < count; j += 256) {
            uint v = in[j];
            buf[v & (FB - 1)] = (int)(v >> FB_LOG);
        }
        __syncthreads();
        for (int j = threadIdx.x; j < count; j += 256)
            col[cstart + j] = buf[j];
    }
}

__global__ void scan1(int* __restrict__ a, int* __restrict__ bsum, int n) {
    __shared__ int ws[16];
    int i = blockIdx.x * SCAN_B + threadIdx.x;
    int lane = threadIdx.x & 63, wid = threadIdx.x >> 6;
    int v = (i < n) ? a[i] : 0;
    int incl = v;
    #pragma unroll
    for (int off = 1; off < 64; off <<= 1) {
        int t = __shfl_up(incl, off, 64);
        if (lane >= off) incl += t;
    }
    if (lane == 63) ws[wid] = incl;
    __syncthreads();
    int woff = 0;
    for (int w = 0; w < wid; ++w) woff += ws[w];
    if (i < n) a[i] = woff + incl - v;
    if (threadIdx.x == SCAN_B - 1) bsum[blockIdx.x] = woff + incl;
}

__global__ void scan2(int* __restrict__ bsum, int nb) {
    __shared__ int ws[16];
    int lane = threadIdx.x & 63, wid = threadIdx.x >> 6;
    int v = ((int)threadIdx.x < nb) ? bsum[threadIdx.x] : 0;
    int incl = v;
    #pragma unroll
    for (int off = 1; off < 64; off <<= 1) {
        int t = __shfl_up(incl, off, 64);
        if (lane >= off) incl += t;
    }
    if (lane == 63) ws[wid] = incl;
    __syncthreads();
    int woff = 0;
    for (int w = 0; w < wid; ++w) woff += ws[w];
    if ((int)threadIdx.x < nb) bsum[threadIdx.x] = woff + incl - v;
}

__global__ void scan3(int* __restrict__ cur, const int* __restrict__ bsum, int n) {
    int i = blockIdx.x * SCAN_B + threadIdx.x;
    if (i < n) cur[i] += bsum[blockIdx.x];
}

// ---- 128B-row gather (one wave per node; r=lane>>3 row slot, c=lane&7 chunk).
// ends[-1] must be valid (sentinel). COMBINE=0: bf16 out at (ob_pitch, ob_off).
// COMBINE=1: outf = (x0 + x1 + mean)/3, x1 bf16 at (x1_pitch, x1_off).
// NOTE: outf may alias x1's buffer (same row, same wave) — data dependency
// (store value uses loaded x1) keeps this safe; no __restrict__ on those.
template <int COMBINE>
__global__ __launch_bounds__(256) void gather128(
        const ushort* __restrict__ feat,
        const int* __restrict__ ends,
        const int* __restrict__ col,
        const float* __restrict__ x0,
        const ushort* x1, int x1_pitch, int x1_off,
        float* outf,
        ushort* outb, int ob_pitch, int ob_off,
        int n) {
    int node = blockIdx.x * 4 + (threadIdx.x >> 6);
    if (node >= n) return;
    int lane = threadIdx.x & 63;
    int r = lane >> 3, c = lane & 7;
    int beg = ends[node - 1];
    int end = ends[node];
    const ushort* fbase = feat + c * 8;

    float acc[8];
    #pragma unroll
    for (int j = 0; j < 8; ++j) acc[j] = 0.0f;

    for (int e = beg; e < end; e += 16) {
        int i0 = e + r, i1 = e + 8 + r;
        bool ok0 = i0 < end, ok1 = i1 < end;
        int nb0 = col[ok0 ? i0 : beg];
        int nb1 = col[ok1 ? i1 : beg];
        uint4 v0 = *(const uint4*)(fbase + (size_t)nb0 * DIM);
        uint4 v1 = *(const uint4*)(fbase + (size_t)nb1 * DIM);
        if (ok0) {
            acc[0] += bf16_lo(v0.x); acc[1] += bf16_hi(v0.x);
            acc[2] += bf16_lo(v0.y); acc[3] += bf16_hi(v0.y);
            acc[4] += bf16_lo(v0.z); acc[5] += bf16_hi(v0.z);
            acc[6] += bf16_lo(v0.w); acc[7] += bf16_hi(v0.w);
        }
        if (ok1) {
            acc[0] += bf16_lo(v1.x); acc[1] += bf16_hi(v1.x);
            acc[2] += bf16_lo(v1.y); acc[3] += bf16_hi(v1.y);
            acc[4] += bf16_lo(v1.z); acc[5] += bf16_hi(v1.z);
            acc[6] += bf16_lo(v1.w); acc[7] += bf16_hi(v1.w);
        }
    }
    #pragma unroll
    for (int m = 8; m < 64; m <<= 1) {
        #pragma unroll
        for (int j = 0; j < 8; ++j) acc[j] += __shfl_xor(acc[j], m, 64);
    }
    if (r == 0) {
        int d = end - beg;
        float inv = (d > 0) ? 1.0f / (float)d : 0.0f;
        if (COMBINE) {
            size_t base = (size_t)node * DIM + c * 8;
            float4 xa = *(const float4*)(x0 + base);
            float4 xb = *(const float4*)(x0 + base + 4);
            uint4  xq = *(const uint4*)(x1 + (size_t)node * x1_pitch + x1_off + c * 8);
            float4 oa, ob;
            oa.x = (xa.x + bf16_lo(xq.x) + acc[0] * inv) * (1.0f / 3.0f);
            oa.y = (xa.y + bf16_hi(xq.x) + acc[1] * inv) * (1.0f / 3.0f);
            oa.z = (xa.z + bf16_lo(xq.y) + acc[2] * inv) * (1.0f / 3.0f);
            oa.w = (xa.w + bf16_hi(xq.y) + acc[3] * inv) * (1.0f / 3.0f);
            ob.x = (xb.x + bf16_lo(xq.z) + acc[4] * inv) * (1.0f / 3.0f);
            ob.y = (xb.y + bf16_hi(xq.z) + acc[5] * inv) * (1.0f / 3.0f);
            ob.z = (xb.z + bf16_lo(xq.w) + acc[6] * inv) * (1.0f / 3.0f);
            ob.w = (xb.w + bf16_hi(xq.w) + acc[7] * inv) * (1.0f / 3.0f);
            *(float4*)(outf + base)     = oa;
            *(float4*)(outf + base + 4) = ob;
        } else {
            uint4 o;
            o.x = f2b(acc[0] * inv) | (f2b(acc[1] * inv) << 16);
            o.y = f2b(acc[2] * inv) | (f2b(acc[3] * inv) << 16);
            o.z = f2b(acc[4] * inv) | (f2b(acc[5] * inv) << 16);
            o.w = f2b(acc[6] * inv) | (f2b(acc[7] * inv) << 16);
            *(uint4*)(outb + (size_t)node * ob_pitch + ob_off + c * 8) = o;
        }
    }
}

// ---- 256B-row fused item pass: feat = u01 (u0|u1 interleaved, pitch 128).
// Computes i1 = mean(u0-nbrs), i2 = mean(u1-nbrs) in ONE col walk.
// outf = (x0 + i1 + i2)/3 (f32), outb = bf16(i1) (dense pitch 64).
__global__ __launch_bounds__(256) void gather256_combine(
        const ushort* __restrict__ feat,
        const int* __restrict__ ends,
        const int* __restrict__ col,
        const float* __restrict__ x0,
        float* __restrict__ outf,
        ushort* __restrict__ outb,
        int n) {
    int node = blockIdx.x * 4 + (threadIdx.x >> 6);
    if (node >= n) return;
    int lane = threadIdx.x & 63;
    int c = lane & 15, r = lane >> 4;          // c: 16B chunk of 256B row
    int beg = ends[node - 1];
    int end = ends[node];
    const ushort* fbase = feat + c * 8;

    float acc[8];
    #pragma unroll
    for (int j = 0; j < 8; ++j) acc[j] = 0.0f;

    for (int e = beg; e < end; e += 8) {
        int i0 = e + r, i1 = e + 4 + r;
        bool ok0 = i0 < end, ok1 = i1 < end;
        int nb0 = col[ok0 ? i0 : beg];
        int nb1 = col[ok1 ? i1 : beg];
        uint4 v0 = *(const uint4*)(fbase + (size_t)nb0 * 128);
        uint4 v1 = *(const uint4*)(fbase + (size_t)nb1 * 128);
        if (ok0) {
            acc[0] += bf16_lo(v0.x); acc[1] += bf16_hi(v0.x);
            acc[2] += bf16_lo(v0.y); acc[3] += bf16_hi(v0.y);
            acc[4] += bf16_lo(v0.z); acc[5] += bf16_hi(v0.z);
            acc[6] += bf16_lo(v0.w); acc[7] += bf16_hi(v0.w);
        }
        if (ok1) {
            acc[0] += bf16_lo(v1.x); acc[1] += bf16_hi(v1.x);
            acc[2] += bf16_lo(v1.y); acc[3] += bf16_hi(v1.y);
            acc[4] += bf16_lo(v1.z); acc[5] += bf16_hi(v1.z);
            acc[6] += bf16_lo(v1.w); acc[7] += bf16_hi(v1.w);
        }
    }
    // fold the 4 r-slots (lane bits 4,5)
    #pragma unroll
    for (int m = 16; m < 64; m <<= 1) {
        #pragma unroll
        for (int j = 0; j < 8; ++j) acc[j] += __shfl_xor(acc[j], m, 64);
    }
    // partner exchange: lane c (<8, u0-part) pairs with lane c+8 (u1-part, same elems)
    float b8[8];
    #pragma unroll
    for (int j = 0; j < 8; ++j) b8[j] = __shfl_xor(acc[j], 8, 64);

    if (r == 0 && c < 8) {
        int d = end - beg;
        float inv = (d > 0) ? 1.0f / (float)d : 0.0f;
        size_t base = (size_t)node * DIM + c * 8;
        float4 xa = *(const float4*)(x0 + base);
        float4 xb = *(const float4*)(x0 + base + 4);
        float i1v[8];
        #pragma unroll
        for (int j = 0; j < 8; ++j) i1v[j] = acc[j] * inv;
        float4 oa, ob;
        oa.x = (xa.x + i1v[0] + b8[0] * inv) * (1.0f / 3.0f);
        oa.y = (xa.y + i1v[1] + b8[1] * inv) * (1.0f / 3.0f);
        oa.z = (xa.z + i1v[2] + b8[2] * inv) * (1.0f / 3.0f);
        oa.w = (xa.w + i1v[3] + b8[3] * inv) * (1.0f / 3.0f);
        ob.x = (xb.x + i1v[4] + b8[4] * inv) * (1.0f / 3.0f);
        ob.y = (xb.y + i1v[5] + b8[5] * inv) * (1.0f / 3.0f);
        ob.z = (xb.z + i1v[6] + b8[6] * inv) * (1.0f / 3.0f);
        ob.w = (xb.w + i1v[7] + b8[7] * inv) * (1.0f / 3.0f);
        *(float4*)(outf + base)     = oa;
        *(float4*)(outf + base + 4) = ob;
        uint4 q;
        q.x = f2b(i1v[0]) | (f2b(i1v[1]) << 16);
        q.y = f2b(i1v[2]) | (f2b(i1v[3]) << 16);
        q.z = f2b(i1v[4]) | (f2b(i1v[5]) << 16);
        q.w = f2b(i1v[6]) | (f2b(i1v[7]) << 16);
        *(uint4*)(outb + base) = q;
    }
}

extern "C" void kernel_launch(void* const* d_in, const int* in_sizes, int n_in,
                              void* d_out, int out_size, void* d_ws, size_t ws_size,
                              hipStream_t stream) {
    const float* u0  = (const float*)d_in[0];
    const float* i0  = (const float*)d_in[1];
    const int*   src = (const int*)d_in[2];
    const int*   dst = (const int*)d_in[3];

    const int n_users = in_sizes[0] / DIM;   // 200000
    const int n_items = in_sizes[1] / DIM;   // 100000
    const int E       = in_sizes[2];         // 3000000
    const int n_nodes = n_users + n_items;
    const int uchunk  = (n_users + NG - 1) / NG;   // 25000 (< 2^15: packing req)
    const int ichunk  = (n_items + NG - 1) / NG;   // 12500 (< 2^14: packing req)

    const size_t u_elems = (size_t)n_users * DIM;
    const size_t i_elems = (size_t)n_items * DIM;

    // Workspace (~38 MB):
    //   cur_full[n_nodes+1] | gcnt[16] cursor[16] bstart[20] fstart[20]
    //   cursor2[768] | col[2E] | bsum[1024] | ib[i_elems bf16]
    int* cur_full = (int*)d_ws;       // [0] = 0 sentinel, deg = cur_full+1
    int* deg     = cur_full + 1;
    int* gcnt    = cur_full + (n_nodes + 1);
    int* cursor  = gcnt + 16;
    int* bstart  = cursor + 16;       // 17 ints + 3 pad
    int* fstart  = bstart + 20;       // 17 ints + 3 pad
    int* cursor2 = fstart + 20;       // up to 749 ints
    int* col     = cursor2 + 768;
    int* bsum    = col + 2 * (size_t)E;
    ushort* ib   = (ushort*)(bsum + 1024);  // i0 bf16, later overwritten by i1 bf16

    // d_out: user region doubles as bins2 (24.5 MB) during CSR build, then as
    // u01 (u0|u1 interleaved bf16, 256B rows). item region (out_i, 25.6 MB)
    // doubles as the phase-1 bin array (24 MB) — dead until gather256_combine.
    float* out_u = (float*)d_out;
    float* out_i = out_u + u_elems;
    ushort* u01  = (ushort*)d_out;         // exactly overlays out_u (51.2 MB)
    uint*  bins  = (uint*)out_i;
    uint*  bins2 = (uint*)d_out;

    const int BLK = 256;
    const int nb = (n_nodes + SCAN_B - 1) / SCAN_B;
    const int etiles = (E + BLK * EPT - 1) / (BLK * EPT);
    const int nfmax = (2 * E + FB - 1) / FB + 16;   // 749

    // ---- CSR build: hist -> scan16 -> bin -> node scans -> fine bin -> fill
    hipMemsetAsync(cur_full, 0, (size_t)(n_nodes + 1 + 16) * sizeof(int), stream);
    edge_hist<<<etiles, BLK, 0, stream>>>(src, dst, deg, gcnt, n_users, E, uchunk, ichunk);
    scan16<<<1, BLK, 0, stream>>>(gcnt, cursor, bstart, fstart, cursor2);
    bin_edges<<<etiles, BLK, 0, stream>>>(src, dst, cursor, bins, E, uchunk, ichunk);
    scan1<<<nb, SCAN_B, 0, stream>>>(deg, bsum, n_nodes);
    scan2<<<1, SCAN_B, 0, stream>>>(bsum, nb);
    scan3<<<nb, SCAN_B, 0, stream>>>(deg, bsum, n_nodes);
    bin_fine<<<16 * 32, BLK, 0, stream>>>(bins, bstart, fstart, deg, cursor2, bins2,
                                          n_users, uchunk, ichunk);
    fill_fine<<<nfmax, BLK, 0, stream>>>(bins2, bstart, fstart, col);
    // deg now holds inclusive segment ends (users: [0..), items at deg+n_users).

    // ---- stage bf16 (bins/bins2 regions are dead from here on) ----
    cvt_bf16_pitch<<<(int)((u_elems / 8 + BLK - 1) / BLK), BLK, 0, stream>>>(
        u0, u01, (int)(u_elems / 8), 128, 0);
    cvt_bf16_pitch<<<(int)((i_elems / 8 + BLK - 1) / BLK), BLK, 0, stream>>>(
        i0, ib, (int)(i_elems / 8), 64, 0);

    const int ug = (n_users + 3) / 4;
    const int ig = (n_items + 3) / 4;

    // ---- Pass A: u1 = mean(i0-nbrs) -> u01 odd halves (bf16) ----
    gather128<0><<<ug, BLK, 0, stream>>>(ib, deg, col, nullptr,
                                         nullptr, 0, 0, nullptr,
                                         u01, 128, 64, n_users);

    // ---- Pass C: fused item pass: out_i = (i0 + i1 + i2)/3, ib <- bf16(i1) ----
    gather256_combine<<<ig, BLK, 0, stream>>>(u01, deg + n_users, col,
                                              i0, out_i, ib, n_items);

    // ---- Pass D: out_u = (u0 + u1 + mean(i1-nbrs))/3 (u1 from u01 odd) ----
    gather128<1><<<ug, BLK, 0, stream>>>(ib, deg, col, u0,
                                         u01, 128, 64, out_u,
                                         nullptr, 0, 0, n_users);
}

// Round 5
// 971.497 us; speedup vs baseline: 1.0381x; 1.0381x over previous
//
#include <hip/hip_runtime.h>

#define DIM 64
#define NG 8
#define SCAN_B 1024
#define EPT 8      // edges per thread in hist/bin kernels (tile = 256*EPT = 2048)
#define FB_LOG 13
#define FB 8192    // fine-bucket size: 8192 col slots = 32 KB
#define MAXNF 384  // max fine buckets per coarse bucket (ceil(3e6/8192)=367)
#define TILE2 4096 // entries per bin_fine tile

typedef unsigned int uint;
typedef unsigned short ushort;
typedef unsigned char uchar;

// ---- bf16 helpers ----
__device__ __forceinline__ float bf16_lo(uint u) {
    union { uint u; float f; } c; c.u = u << 16; return c.f;
}
__device__ __forceinline__ float bf16_hi(uint u) {
    union { uint u; float f; } c; c.u = u & 0xffff0000u; return c.f;
}
__device__ __forceinline__ uint f2b(float f) {   // bf16 in low 16 bits (RNE)
    union { float f; uint u; } c; c.f = f;
    return (c.u + 0x7fffu + ((c.u >> 16) & 1u)) >> 16;
}

// f32 -> bf16, 8 elems/thread, output row pitch/offset in ushorts (rows of 64).
__global__ void cvt_bf16_pitch(const float* __restrict__ in, ushort* __restrict__ out,
                               int n8, int pitch, int off) {
    int k = blockIdx.x * blockDim.x + threadIdx.x;
    if (k >= n8) return;
    int row = k >> 3, g = k & 7;
    const float4* p = (const float4*)in + (size_t)k * 2;
    float4 a = p[0], b = p[1];
    uint4 o;
    o.x = f2b(a.x) | (f2b(a.y) << 16);
    o.y = f2b(a.z) | (f2b(a.w) << 16);
    o.z = f2b(b.x) | (f2b(b.y) << 16);
    o.w = f2b(b.z) | (f2b(b.w) << 16);
    *(uint4*)(out + (size_t)row * pitch + off + g * 8) = o;
}

// ---- CSR build ----
// Per-node degree histogram + per-group (16-bucket) edge counts.
__global__ __launch_bounds__(256) void edge_hist(
        const int* __restrict__ src, const int* __restrict__ dst,
        int* __restrict__ deg, int* __restrict__ gcnt,
        int n_users, int E, int uchunk, int ichunk) {
    __shared__ int h[16];
    if (threadIdx.x < 16) h[threadIdx.x] = 0;
    __syncthreads();
    int t0 = blockIdx.x * (256 * EPT) + threadIdx.x;
    #pragma unroll
    for (int k = 0; k < EPT; ++k) {
        int e = t0 + k * 256;
        if (e < E) {
            int s = src[e], t = dst[e];
            atomicAdd(&deg[s], 1);
            atomicAdd(&deg[n_users + t], 1);
            atomicAdd(&h[s / uchunk], 1);
            atomicAdd(&h[8 + t / ichunk], 1);
        }
    }
    __syncthreads();
    if (threadIdx.x < 16) {
        int v = h[threadIdx.x];
        if (v) atomicAdd(&gcnt[threadIdx.x], v);
    }
}

// Exclusive scan of the 16 bucket counts -> bucket bases (col space == bins
// space), fine-bucket bases (fstart), and cursor2[f] = f*FB (bins2 slots).
__global__ void scan16(const int* __restrict__ gcnt, int* __restrict__ cursor,
                       int* __restrict__ bstart, int* __restrict__ fstart,
                       int* __restrict__ cursor2) {
    if (threadIdx.x == 0) {
        int run = 0, frun = 0;
        for (int b = 0; b < 16; ++b) {
            bstart[b] = run;
            cursor[b] = run;
            fstart[b] = frun;
            run  += gcnt[b];
            frun += (gcnt[b] + FB - 1) >> FB_LOG;
        }
        bstart[16] = run;    // == 2E
        fstart[16] = frun;   // total fine buckets
    }
    __syncthreads();
    int nf = fstart[16];
    for (int f = threadIdx.x; f < nf; f += blockDim.x)
        cursor2[f] = f << FB_LOG;
}

// Phase 1: single read of the edge list; each edge yields one entry in its
// user-group bucket and one in its item-group bucket:
//   user word: s_local | (t << 15)   (uchunk=25000 < 2^15, t < 2^17)
//   item word: t_local | (s << 14)   (ichunk=12500 < 2^14, s < 2^18)
// Entries are staged bucket-sorted in LDS, then copied out FLAT by consecutive
// threads -> consecutive global addresses within each ~1KB bucket run ->
// full-line coalesced stores (store-issue adjacency, not just address density,
// is what kills 64B-line write amplification on this chip).
__global__ __launch_bounds__(256) void bin_edges(
        const int* __restrict__ src, const int* __restrict__ dst,
        int* __restrict__ cursor, uint* __restrict__ bins,
        int E, int uchunk, int ichunk) {
    __shared__ int cnt[16];
    __shared__ int lbase[17];
    __shared__ int gdelta[16];
    __shared__ uint ord[2 * 256 * EPT];    // 4096 entries, 16 KB
    __shared__ uchar bkt[2 * 256 * EPT];   // 4 KB
    if (threadIdx.x < 16) cnt[threadIdx.x] = 0;
    __syncthreads();
    int t0 = blockIdx.x * (256 * EPT) + threadIdx.x;
    uint wu[EPT], wi[EPT];
    int bu[EPT], bi[EPT], ou[EPT], oi[EPT];
    #pragma unroll
    for (int k = 0; k < EPT; ++k) {
        int e = t0 + k * 256;
        bu[k] = -1;
        if (e < E) {
            int s = src[e], t = dst[e];
            bu[k] = s / uchunk;
            bi[k] = t / ichunk;
            wu[k] = (uint)(s - bu[k] * uchunk) | ((uint)t << 15);
            wi[k] = (uint)(t - bi[k] * ichunk) | ((uint)s << 14);
            ou[k] = atomicAdd(&cnt[bu[k]], 1);
            oi[k] = atomicAdd(&cnt[8 + bi[k]], 1);
        }
    }
    __syncthreads();
    if (threadIdx.x == 0) {
        int run = 0;
        for (int b = 0; b < 16; ++b) { lbase[b] = run; run += cnt[b]; }
        lbase[16] = run;
    }
    __syncthreads();
    if (threadIdx.x < 16) {
        int c = cnt[threadIdx.x];
        gdelta[threadIdx.x] = (c ? atomicAdd(&cursor[threadIdx.x], c) : 0)
                              - lbase[threadIdx.x];
    }
    #pragma unroll
    for (int k = 0; k < EPT; ++k) {
        if (bu[k] >= 0) {
            int ju = lbase[bu[k]] + ou[k];
            ord[ju] = wu[k]; bkt[ju] = (uchar)bu[k];
            int ji = lbase[8 + bi[k]] + oi[k];
            ord[ji] = wi[k]; bkt[ji] = (uchar)(8 + bi[k]);
        }
    }
    __syncthreads();
    int tot = lbase[16];
    for (int j = threadIdx.x; j < tot; j += 256)
        bins[gdelta[bkt[j]] + j] = ord[j];
}

// Phase 2: per coarse bucket, assign each entry its exact col slot via the deg
// cursor atomic, then re-bin by 8192-slot fine bucket (col window) as
//   word = (pos_rel & 8191) | (neighbor << 13)    (13+18 = 31 bits max)
// Same LDS-staged flat copy-out: ~360B runs per fine bucket per tile, written
// by consecutive threads -> coalesced.
__global__ __launch_bounds__(256) void bin_fine(
        const uint* __restrict__ bins, const int* __restrict__ bstart,
        const int* __restrict__ fstart, int* __restrict__ deg,
        int* __restrict__ cursor2, uint* __restrict__ bins2,
        int n_users, int uchunk, int ichunk) {
    __shared__ int cnt[MAXNF];
    __shared__ int lbase[MAXNF + 1];
    __shared__ int gdelta[MAXNF];
    __shared__ uint ord[TILE2];     // 16 KB
    __shared__ ushort bkt[TILE2];   // 8 KB
    const int b   = blockIdx.x & 15;
    const int bi  = blockIdx.x >> 4;
    const int bpb = gridDim.x >> 4;
    const int lo = bstart[b], hi = bstart[b + 1];
    if (lo >= hi) return;
    const int nf  = (hi - lo + FB - 1) >> FB_LOG;
    const int fb0 = fstart[b];
    const int nodebase = (b < 8) ? b * uchunk : n_users + (b - 8) * ichunk;
    const uint lmask  = (b < 8) ? 32767u : 16383u;
    const int  lshift = (b < 8) ? 15 : 14;
    const int ntiles = (hi - lo + TILE2 - 1) / TILE2;
    for (int tile = bi; tile < ntiles; tile += bpb) {
        const int tbeg = lo + tile * TILE2;
        const int tend = min(tbeg + TILE2, hi);
        for (int j = threadIdx.x; j < nf; j += 256) cnt[j] = 0;
        __syncthreads();
        uint w[16]; int kf[16]; int off[16];
        #pragma unroll
        for (int k = 0; k < 16; ++k) {
            int idx = tbeg + k * 256 + threadIdx.x;
            kf[k] = -1;
            if (idx < tend) {
                uint ww = bins[idx];
                int node = nodebase + (int)(ww & lmask);
                uint nbr = ww >> lshift;
                int pos = atomicAdd(&deg[node], 1);
                int rel = pos - lo;
                kf[k]  = rel >> FB_LOG;
                w[k]   = (uint)(rel & (FB - 1)) | (nbr << FB_LOG);
                off[k] = atomicAdd(&cnt[kf[k]], 1);
            }
        }
        __syncthreads();
        if (threadIdx.x == 0) {
            int run = 0;
            for (int j = 0; j < nf; ++j) { lbase[j] = run; run += cnt[j]; }
            lbase[nf] = run;
        }
        __syncthreads();
        for (int j = threadIdx.x; j < nf; j += 256) {
            int c = cnt[j];
            gdelta[j] = (c ? atomicAdd(&cursor2[fb0 + j], c) : 0) - lbase[j];
        }
        #pragma unroll
        for (int k = 0; k < 16; ++k) {
            if (kf[k] >= 0) {
                int j = lbase[kf[k]] + off[k];
                ord[j] = w[k]; bkt[j] = (ushort)kf[k];
            }
        }
        __syncthreads();
        int tot = lbase[nf];
        for (int j = threadIdx.x; j < tot; j += 256)
            bins2[gdelta[bkt[j]] + j] = ord[j];
        __syncthreads();   // protect cnt/ord/bkt before next tile
    }
}

// Phase 3: one block per fine bucket. Dense read of its 8192 packed entries,
// collision-free LDS scatter by the carried 13-bit local slot, then ONE dense
// 32 KB write to col — full lines only, zero write amplification.
__global__ __launch_bounds__(256) void fill_fine(
        const uint* __restrict__ bins2, const int* __restrict__ bstart,
        const int* __restrict__ fstart, int* __restrict__ col) {
    __shared__ int buf[FB];
    const int f = blockIdx.x;
    if (f >= fstart[16]) return;
    int b = 0;
    #pragma unroll
    for (int j = 1; j < 16; ++j) if (fstart[j] <= f) b = j;
    const int k = f - fstart[b];
    const int cstart = bstart[b] + (k << FB_LOG);
    const int count = min(FB, bstart[b + 1] - cstart);
    const uint* in = bins2 + (size_t)f * FB;
    if (count == FB) {
        #pragma unroll
        for (int q = 0; q < 8; ++q) {
            uint4 v = *((const uint4*)in + q * 256 + threadIdx.x);
            buf[v.x & (FB - 1)] = (int)(v.x >> FB_LOG);
            buf[v.y & (FB - 1)] = (int)(v.y >> FB_LOG);
            buf[v.z & (FB - 1)] = (int)(v.z >> FB_LOG);
            buf[v.w & (FB - 1)] = (int)(v.w >> FB_LOG);
        }
        __syncthreads();
        #pragma unroll
        for (int q = 0; q < 8; ++q) {
            int j = (q * 256 + threadIdx.x) * 4;
            int4 o; o.x = buf[j]; o.y = buf[j + 1]; o.z = buf[j + 2]; o.w = buf[j + 3];
            *(int4*)(col + cstart + j) = o;
        }
    } else {
        for (int j = threadIdx.x; j < count; j += 256) {
            uint v = in[j];
            buf[v & (FB - 1)] = (int)(v >> FB_LOG);
        }
        __syncthreads();
        for (int j = threadIdx.x; j < count; j += 256)
            col[cstart + j] = buf[j];
    }
}

__global__ void scan1(int* __restrict__ a, int* __restrict__ bsum, int n) {
    __shared__ int ws[16];
    int i = blockIdx.x * SCAN_B + threadIdx.x;
    int lane = threadIdx.x & 63, wid = threadIdx.x >> 6;
    int v = (i < n) ? a[i] : 0;
    int incl = v;
    #pragma unroll
    for (int off = 1; off < 64; off <<= 1) {
        int t = __shfl_up(incl, off, 64);
        if (lane >= off) incl += t;
    }
    if (lane == 63) ws[wid] = incl;
    __syncthreads();
    int woff = 0;
    for (int w = 0; w < wid; ++w) woff += ws[w];
    if (i < n) a[i] = woff + incl - v;
    if (threadIdx.x == SCAN_B - 1) bsum[blockIdx.x] = woff + incl;
}

__global__ void scan2(int* __restrict__ bsum, int nb) {
    __shared__ int ws[16];
    int lane = threadIdx.x & 63, wid = threadIdx.x >> 6;
    int v = ((int)threadIdx.x < nb) ? bsum[threadIdx.x] : 0;
    int incl = v;
    #pragma unroll
    for (int off = 1; off < 64; off <<= 1) {
        int t = __shfl_up(incl, off, 64);
        if (lane >= off) incl += t;
    }
    if (lane == 63) ws[wid] = incl;
    __syncthreads();
    int woff = 0;
    for (int w = 0; w < wid; ++w) woff += ws[w];
    if ((int)threadIdx.x < nb) bsum[threadIdx.x] = woff + incl - v;
}

__global__ void scan3(int* __restrict__ cur, const int* __restrict__ bsum, int n) {
    int i = blockIdx.x * SCAN_B + threadIdx.x;
    if (i < n) cur[i] += bsum[blockIdx.x];
}

// ---- 128B-row gather (one wave per node; r=lane>>3 row slot, c=lane&7 chunk).
// ends[-1] must be valid (sentinel). COMBINE=0: bf16 out at (ob_pitch, ob_off).
// COMBINE=1: outf = (x0 + x1 + mean)/3, x1 bf16 at (x1_pitch, x1_off).
// NOTE: outf may alias x1's buffer (same row, same wave) — data dependency
// (store value uses loaded x1) keeps this safe; no __restrict__ on those.
template <int COMBINE>
__global__ __launch_bounds__(256) void gather128(
        const ushort* __restrict__ feat,
        const int* __restrict__ ends,
        const int* __restrict__ col,
        const float* __restrict__ x0,
        const ushort* x1, int x1_pitch, int x1_off,
        float* outf,
        ushort* outb, int ob_pitch, int ob_off,
        int n) {
    int node = blockIdx.x * 4 + (threadIdx.x >> 6);
    if (node >= n) return;
    int lane = threadIdx.x & 63;
    int r = lane >> 3, c = lane & 7;
    int beg = ends[node - 1];
    int end = ends[node];
    const ushort* fbase = feat + c * 8;

    float acc[8];
    #pragma unroll
    for (int j = 0; j < 8; ++j) acc[j] = 0.0f;

    for (int e = beg; e < end; e += 16) {
        int i0 = e + r, i1 = e + 8 + r;
        bool ok0 = i0 < end, ok1 = i1 < end;
        int nb0 = col[ok0 ? i0 : beg];
        int nb1 = col[ok1 ? i1 : beg];
        uint4 v0 = *(const uint4*)(fbase + (size_t)nb0 * DIM);
        uint4 v1 = *(const uint4*)(fbase + (size_t)nb1 * DIM);
        if (ok0) {
            acc[0] += bf16_lo(v0.x); acc[1] += bf16_hi(v0.x);
            acc[2] += bf16_lo(v0.y); acc[3] += bf16_hi(v0.y);
            acc[4] += bf16_lo(v0.z); acc[5] += bf16_hi(v0.z);
            acc[6] += bf16_lo(v0.w); acc[7] += bf16_hi(v0.w);
        }
        if (ok1) {
            acc[0] += bf16_lo(v1.x); acc[1] += bf16_hi(v1.x);
            acc[2] += bf16_lo(v1.y); acc[3] += bf16_hi(v1.y);
            acc[4] += bf16_lo(v1.z); acc[5] += bf16_hi(v1.z);
            acc[6] += bf16_lo(v1.w); acc[7] += bf16_hi(v1.w);
        }
    }
    #pragma unroll
    for (int m = 8; m < 64; m <<= 1) {
        #pragma unroll
        for (int j = 0; j < 8; ++j) acc[j] += __shfl_xor(acc[j], m, 64);
    }
    if (r == 0) {
        int d = end - beg;
        float inv = (d > 0) ? 1.0f / (float)d : 0.0f;
        if (COMBINE) {
            size_t base = (size_t)node * DIM + c * 8;
            float4 xa = *(const float4*)(x0 + base);
            float4 xb = *(const float4*)(x0 + base + 4);
            uint4  xq = *(const uint4*)(x1 + (size_t)node * x1_pitch + x1_off + c * 8);
            float4 oa, ob;
            oa.x = (xa.x + bf16_lo(xq.x) + acc[0] * inv) * (1.0f / 3.0f);
            oa.y = (xa.y + bf16_hi(xq.x) + acc[1] * inv) * (1.0f / 3.0f);
            oa.z = (xa.z + bf16_lo(xq.y) + acc[2] * inv) * (1.0f / 3.0f);
            oa.w = (xa.w + bf16_hi(xq.y) + acc[3] * inv) * (1.0f / 3.0f);
            ob.x = (xb.x + bf16_lo(xq.z) + acc[4] * inv) * (1.0f / 3.0f);
            ob.y = (xb.y + bf16_hi(xq.z) + acc[5] * inv) * (1.0f / 3.0f);
            ob.z = (xb.z + bf16_lo(xq.w) + acc[6] * inv) * (1.0f / 3.0f);
            ob.w = (xb.w + bf16_hi(xq.w) + acc[7] * inv) * (1.0f / 3.0f);
            *(float4*)(outf + base)     = oa;
            *(float4*)(outf + base + 4) = ob;
        } else {
            uint4 o;
            o.x = f2b(acc[0] * inv) | (f2b(acc[1] * inv) << 16);
            o.y = f2b(acc[2] * inv) | (f2b(acc[3] * inv) << 16);
            o.z = f2b(acc[4] * inv) | (f2b(acc[5] * inv) << 16);
            o.w = f2b(acc[6] * inv) | (f2b(acc[7] * inv) << 16);
            *(uint4*)(outb + (size_t)node * ob_pitch + ob_off + c * 8) = o;
        }
    }
}

// ---- 256B-row fused item pass: feat = u01 (u0|u1 interleaved, pitch 128).
// Computes i1 = mean(u0-nbrs), i2 = mean(u1-nbrs) in ONE col walk.
// outf = (x0 + i1 + i2)/3 (f32), outb = bf16(i1) (dense pitch 64).
__global__ __launch_bounds__(256) void gather256_combine(
        const ushort* __restrict__ feat,
        const int* __restrict__ ends,
        const int* __restrict__ col,
        const float* __restrict__ x0,
        float* __restrict__ outf,
        ushort* __restrict__ outb,
        int n) {
    int node = blockIdx.x * 4 + (threadIdx.x >> 6);
    if (node >= n) return;
    int lane = threadIdx.x & 63;
    int c = lane & 15, r = lane >> 4;          // c: 16B chunk of 256B row
    int beg = ends[node - 1];
    int end = ends[node];
    const ushort* fbase = feat + c * 8;

    float acc[8];
    #pragma unroll
    for (int j = 0; j < 8; ++j) acc[j] = 0.0f;

    for (int e = beg; e < end; e += 8) {
        int i0 = e + r, i1 = e + 4 + r;
        bool ok0 = i0 < end, ok1 = i1 < end;
        int nb0 = col[ok0 ? i0 : beg];
        int nb1 = col[ok1 ? i1 : beg];
        uint4 v0 = *(const uint4*)(fbase + (size_t)nb0 * 128);
        uint4 v1 = *(const uint4*)(fbase + (size_t)nb1 * 128);
        if (ok0) {
            acc[0] += bf16_lo(v0.x); acc[1] += bf16_hi(v0.x);
            acc[2] += bf16_lo(v0.y); acc[3] += bf16_hi(v0.y);
            acc[4] += bf16_lo(v0.z); acc[5] += bf16_hi(v0.z);
            acc[6] += bf16_lo(v0.w); acc[7] += bf16_hi(v0.w);
        }
        if (ok1) {
            acc[0] += bf16_lo(v1.x); acc[1] += bf16_hi(v1.x);
            acc[2] += bf16_lo(v1.y); acc[3] += bf16_hi(v1.y);
            acc[4] += bf16_lo(v1.z); acc[5] += bf16_hi(v1.z);
            acc[6] += bf16_lo(v1.w); acc[7] += bf16_hi(v1.w);
        }
    }
    // fold the 4 r-slots (lane bits 4,5)
    #pragma unroll
    for (int m = 16; m < 64; m <<= 1) {
        #pragma unroll
        for (int j = 0; j < 8; ++j) acc[j] += __shfl_xor(acc[j], m, 64);
    }
    // partner exchange: lane c (<8, u0-part) pairs with lane c+8 (u1-part, same elems)
    float b8[8];
    #pragma unroll
    for (int j = 0; j < 8; ++j) b8[j] = __shfl_xor(acc[j], 8, 64);

    if (r == 0 && c < 8) {
        int d = end - beg;
        float inv = (d > 0) ? 1.0f / (float)d : 0.0f;
        size_t base = (size_t)node * DIM + c * 8;
        float4 xa = *(const float4*)(x0 + base);
        float4 xb = *(const float4*)(x0 + base + 4);
        float i1v[8];
        #pragma unroll
        for (int j = 0; j < 8; ++j) i1v[j] = acc[j] * inv;
        float4 oa, ob;
        oa.x = (xa.x + i1v[0] + b8[0] * inv) * (1.0f / 3.0f);
        oa.y = (xa.y + i1v[1] + b8[1] * inv) * (1.0f / 3.0f);
        oa.z = (xa.z + i1v[2] + b8[2] * inv) * (1.0f / 3.0f);
        oa.w = (xa.w + i1v[3] + b8[3] * inv) * (1.0f / 3.0f);
        ob.x = (xb.x + i1v[4] + b8[4] * inv) * (1.0f / 3.0f);
        ob.y = (xb.y + i1v[5] + b8[5] * inv) * (1.0f / 3.0f);
        ob.z = (xb.z + i1v[6] + b8[6] * inv) * (1.0f / 3.0f);
        ob.w = (xb.w + i1v[7] + b8[7] * inv) * (1.0f / 3.0f);
        *(float4*)(outf + base)     = oa;
        *(float4*)(outf + base + 4) = ob;
        uint4 q;
        q.x = f2b(i1v[0]) | (f2b(i1v[1]) << 16);
        q.y = f2b(i1v[2]) | (f2b(i1v[3]) << 16);
        q.z = f2b(i1v[4]) | (f2b(i1v[5]) << 16);
        q.w = f2b(i1v[6]) | (f2b(i1v[7]) << 16);
        *(uint4*)(outb + base) = q;
    }
}

extern "C" void kernel_launch(void* const* d_in, const int* in_sizes, int n_in,
                              void* d_out, int out_size, void* d_ws, size_t ws_size,
                              hipStream_t stream) {
    const float* u0  = (const float*)d_in[0];
    const float* i0  = (const float*)d_in[1];
    const int*   src = (const int*)d_in[2];
    const int*   dst = (const int*)d_in[3];

    const int n_users = in_sizes[0] / DIM;   // 200000
    const int n_items = in_sizes[1] / DIM;   // 100000
    const int E       = in_sizes[2];         // 3000000
    const int n_nodes = n_users + n_items;
    const int uchunk  = (n_users + NG - 1) / NG;   // 25000 (< 2^15: packing req)
    const int ichunk  = (n_items + NG - 1) / NG;   // 12500 (< 2^14: packing req)

    const size_t u_elems = (size_t)n_users * DIM;
    const size_t i_elems = (size_t)n_items * DIM;

    // Workspace (~38 MB):
    //   cur_full[n_nodes+1] | gcnt[16] cursor[16] bstart[20] fstart[20]
    //   cursor2[768] | col[2E] | bsum[1024] | ib[i_elems bf16]
    int* cur_full = (int*)d_ws;       // [0] = 0 sentinel, deg = cur_full+1
    int* deg     = cur_full + 1;
    int* gcnt    = cur_full + (n_nodes + 1);
    int* cursor  = gcnt + 16;
    int* bstart  = cursor + 16;       // 17 ints + 3 pad
    int* fstart  = bstart + 20;       // 17 ints + 3 pad
    int* cursor2 = fstart + 20;       // up to 749 ints
    int* col     = cursor2 + 768;
    int* bsum    = col + 2 * (size_t)E;
    ushort* ib   = (ushort*)(bsum + 1024);  // i0 bf16, later overwritten by i1 bf16

    // d_out: user region doubles as bins2 (24.5 MB) during CSR build, then as
    // u01 (u0|u1 interleaved bf16, 256B rows). item region (out_i, 25.6 MB)
    // doubles as the phase-1 bin array (24 MB) — dead until gather256_combine.
    float* out_u = (float*)d_out;
    float* out_i = out_u + u_elems;
    ushort* u01  = (ushort*)d_out;         // exactly overlays out_u (51.2 MB)
    uint*  bins  = (uint*)out_i;
    uint*  bins2 = (uint*)d_out;

    const int BLK = 256;
    const int nb = (n_nodes + SCAN_B - 1) / SCAN_B;
    const int etiles = (E + BLK * EPT - 1) / (BLK * EPT);
    const int nfmax = (2 * E + FB - 1) / FB + 16;   // 749

    // ---- CSR build: hist -> scan16 -> bin -> node scans -> fine bin -> fill
    hipMemsetAsync(cur_full, 0, (size_t)(n_nodes + 1 + 16) * sizeof(int), stream);
    edge_hist<<<etiles, BLK, 0, stream>>>(src, dst, deg, gcnt, n_users, E, uchunk, ichunk);
    scan16<<<1, BLK, 0, stream>>>(gcnt, cursor, bstart, fstart, cursor2);
    bin_edges<<<etiles, BLK, 0, stream>>>(src, dst, cursor, bins, E, uchunk, ichunk);
    scan1<<<nb, SCAN_B, 0, stream>>>(deg, bsum, n_nodes);
    scan2<<<1, SCAN_B, 0, stream>>>(bsum, nb);
    scan3<<<nb, SCAN_B, 0, stream>>>(deg, bsum, n_nodes);
    bin_fine<<<16 * 96, BLK, 0, stream>>>(bins, bstart, fstart, deg, cursor2, bins2,
                                          n_users, uchunk, ichunk);
    fill_fine<<<nfmax, BLK, 0, stream>>>(bins2, bstart, fstart, col);
    // deg now holds inclusive segment ends (users: [0..), items at deg+n_users).

    // ---- stage bf16 (bins/bins2 regions are dead from here on) ----
    cvt_bf16_pitch<<<(int)((u_elems / 8 + BLK - 1) / BLK), BLK, 0, stream>>>(
        u0, u01, (int)(u_elems / 8), 128, 0);
    cvt_bf16_pitch<<<(int)((i_elems / 8 + BLK - 1) / BLK), BLK, 0, stream>>>(
        i0, ib, (int)(i_elems / 8), 64, 0);

    const int ug = (n_users + 3) / 4;
    const int ig = (n_items + 3) / 4;

    // ---- Pass A: u1 = mean(i0-nbrs) -> u01 odd halves (bf16) ----
    gather128<0><<<ug, BLK, 0, stream>>>(ib, deg, col, nullptr,
                                         nullptr, 0, 0, nullptr,
                                         u01, 128, 64, n_users);

    // ---- Pass C: fused item pass: out_i = (i0 + i1 + i2)/3, ib <- bf16(i1) ----
    gather256_combine<<<ig, BLK, 0, stream>>>(u01, deg + n_users, col,
                                              i0, out_i, ib, n_items);

    // ---- Pass D: out_u = (u0 + u1 + mean(i1-nbrs))/3 (u1 from u01 odd) ----
    gather128<1><<<ug, BLK, 0, stream>>>(ib, deg, col, u0,
                                         u01, 128, 64, out_u,
                                         nullptr, 0, 0, n_users);
}

// Round 6
// 752.271 us; speedup vs baseline: 1.3406x; 1.2914x over previous
//
#include <hip/hip_runtime.h>

#define DIM 64
#define SCAN_B 1024
#define NBK 256       // node buckets per side (users / items)
#define TEPT 8        // edges per thread in bin_chunked (tile = 2048 edges)
#define TSTRIDE 528   // table row stride in ints (513 used, 64B-aligned rows)
#define LDSBUF 14336  // fill_node staged col entries (56 KB); mean 11719, +24 sigma

typedef unsigned int uint;
typedef unsigned short ushort;

// ---- bf16 helpers ----
__device__ __forceinline__ float bf16_lo(uint u) {
    union { uint u; float f; } c; c.u = u << 16; return c.f;
}
__device__ __forceinline__ float bf16_hi(uint u) {
    union { uint u; float f; } c; c.u = u & 0xffff0000u; return c.f;
}
__device__ __forceinline__ uint f2b(float f) {   // bf16 in low 16 bits (RNE)
    union { float f; uint u; } c; c.f = f;
    return (c.u + 0x7fffu + ((c.u >> 16) & 1u)) >> 16;
}

// f32 -> bf16, 8 elems/thread, output row pitch/offset in ushorts (rows of 64).
__global__ void cvt_bf16_pitch(const float* __restrict__ in, ushort* __restrict__ out,
                               int n8, int pitch, int off) {
    int k = blockIdx.x * blockDim.x + threadIdx.x;
    if (k >= n8) return;
    int row = k >> 3, g = k & 7;
    const float4* p = (const float4*)in + (size_t)k * 2;
    float4 a = p[0], b = p[1];
    uint4 o;
    o.x = f2b(a.x) | (f2b(a.y) << 16);
    o.y = f2b(a.z) | (f2b(a.w) << 16);
    o.z = f2b(b.x) | (f2b(b.y) << 16);
    o.w = f2b(b.z) | (f2b(b.w) << 16);
    *(uint4*)(out + (size_t)row * pitch + off + g * 8) = o;
}

// ---- CSR build, chunked-slab design ----
// One pass over the edge list. Per tile (2048 edges -> 4096 entries):
//  - deg histogram atomics (fire-and-forget, no return dependency)
//  - LDS per-bucket counts (512 buckets: 256 user node-ranges + 256 item)
//  - LDS exclusive scan -> bucket-grouped layout inside the tile's OWN
//    contiguous 16 KB slab (zero write amplification, no global cursors)
//  - per-tile 513-int offset table row (coalesced)
// Entry words: user: (s % nu_pb) | t<<10 (782<2^10, t<2^17 -> 27b)
//              item: (t % ni_pb) | s<<9  (391<2^9,  s<2^18 -> 27b)
__global__ __launch_bounds__(256) void bin_chunked(
        const int* __restrict__ src, const int* __restrict__ dst,
        int* __restrict__ deg, int* __restrict__ table,
        uint* __restrict__ bins, int E, int n_users, int nu_pb, int ni_pb) {
    __shared__ int cnt[2 * NBK];
    __shared__ int lbase[2 * NBK + 1];
    __shared__ uint ord[4096];
    for (int i = threadIdx.x; i < 2 * NBK; i += 256) cnt[i] = 0;
    __syncthreads();
    int t0 = blockIdx.x * (256 * TEPT) + threadIdx.x;
    uint st[2 * TEPT];   // packed (bucket<<12 | local offset), static idx only
    #pragma unroll
    for (int k = 0; k < TEPT; ++k) {
        int e = t0 + k * 256;
        if (e < E) {
            int s = src[e], t = dst[e];
            atomicAdd(&deg[s], 1);
            atomicAdd(&deg[n_users + t], 1);
            int bu = s / nu_pb;
            int bi = t / ni_pb;
            int ou = atomicAdd(&cnt[bu], 1);
            int oi = atomicAdd(&cnt[NBK + bi], 1);
            st[2 * k]     = ((uint)bu << 12) | (uint)ou;
            st[2 * k + 1] = ((uint)(NBK + bi) << 12) | (uint)oi;
        }
    }
    __syncthreads();
    if (threadIdx.x == 0) {
        int run = 0;
        for (int i = 0; i < 2 * NBK; ++i) { lbase[i] = run; run += cnt[i]; }
        lbase[2 * NBK] = run;
    }
    __syncthreads();
    int* trow = table + (size_t)blockIdx.x * TSTRIDE;
    for (int i = threadIdx.x; i <= 2 * NBK; i += 256) trow[i] = lbase[i];
    // phase 2: re-read edges (L1-warm), place into bucket-grouped LDS
    #pragma unroll
    for (int k = 0; k < TEPT; ++k) {
        int e = t0 + k * 256;
        if (e < E) {
            int s = src[e], t = dst[e];
            uint su = st[2 * k], si = st[2 * k + 1];
            int bu = (int)(su >> 12);
            int bi = (int)(si >> 12);
            uint wu = (uint)(s - bu * nu_pb) | ((uint)t << 10);
            uint wi = (uint)(t - (bi - NBK) * ni_pb) | ((uint)s << 9);
            ord[lbase[bu] + (int)(su & 4095u)] = wu;
            ord[lbase[bi] + (int)(si & 4095u)] = wi;
        }
    }
    __syncthreads();
    int tot = lbase[2 * NBK];
    uint* slab = bins + (size_t)blockIdx.x * 4096;
    for (int j = threadIdx.x; j < tot; j += 256)
        slab[j] = ord[j];
}

__global__ void scan1(int* __restrict__ a, int* __restrict__ bsum, int n) {
    __shared__ int ws[16];
    int i = blockIdx.x * SCAN_B + threadIdx.x;
    int lane = threadIdx.x & 63, wid = threadIdx.x >> 6;
    int v = (i < n) ? a[i] : 0;
    int incl = v;
    #pragma unroll
    for (int off = 1; off < 64; off <<= 1) {
        int t = __shfl_up(incl, off, 64);
        if (lane >= off) incl += t;
    }
    if (lane == 63) ws[wid] = incl;
    __syncthreads();
    int woff = 0;
    for (int w = 0; w < wid; ++w) woff += ws[w];
    if (i < n) a[i] = woff + incl - v;
    if (threadIdx.x == SCAN_B - 1) bsum[blockIdx.x] = woff + incl;
}

__global__ void scan2(int* __restrict__ bsum, int nb) {
    __shared__ int ws[16];
    int lane = threadIdx.x & 63, wid = threadIdx.x >> 6;
    int v = ((int)threadIdx.x < nb) ? bsum[threadIdx.x] : 0;
    int incl = v;
    #pragma unroll
    for (int off = 1; off < 64; off <<= 1) {
        int t = __shfl_up(incl, off, 64);
        if (lane >= off) incl += t;
    }
    if (lane == 63) ws[wid] = incl;
    __syncthreads();
    int woff = 0;
    for (int w = 0; w < wid; ++w) woff += ws[w];
    if ((int)threadIdx.x < nb) bsum[threadIdx.x] = woff + incl - v;
}

__global__ void scan3(int* __restrict__ cur, const int* __restrict__ bsum, int n) {
    int i = blockIdx.x * SCAN_B + threadIdx.x;
    if (i < n) cur[i] += bsum[blockIdx.x];
}

__global__ void set_last(int* __restrict__ deg, int n_nodes, int total) {
    if (threadIdx.x == 0) deg[n_nodes] = total;
}

// One block per bucket (512 blocks), exclusive node-range ownership.
// Positions via LDS cursor atomics (bases = deg exclusive-prefix, read-only),
// col segment staged in LDS, written out dense -> zero write amplification.
__global__ __launch_bounds__(256) void fill_node(
        const uint* __restrict__ bins, const int* __restrict__ table,
        const int* __restrict__ deg, int* __restrict__ col,
        int n_users, int n_items, int ntiles, int nu_pb, int ni_pb) {
    __shared__ int cur[800];
    __shared__ int lbuf[LDSBUF];
    int b = blockIdx.x;
    bool user = b < NBK;
    int bb = user ? b : b - NBK;
    int npb = user ? nu_pb : ni_pb;
    int ncnt = user ? n_users : n_items;
    int node0 = bb * npb;
    int nn = min(npb, ncnt - node0);
    if (nn <= 0) return;
    int idx0 = (user ? 0 : n_users) + node0;
    int colbase = deg[idx0];
    int nedge = deg[idx0 + nn] - colbase;
    for (int i = threadIdx.x; i < nn; i += 256)
        cur[i] = deg[idx0 + i] - colbase;
    __syncthreads();
    uint mask = user ? 1023u : 511u;
    int shift = user ? 10 : 9;
    if (nedge <= LDSBUF) {
        for (int t = threadIdx.x; t < ntiles; t += 256) {
            const int* row = table + (size_t)t * TSTRIDE + b;
            int a = row[0], e2 = row[1];
            const uint* slab = bins + (size_t)t * 4096;
            for (int j = a; j < e2; ++j) {
                uint w = slab[j];
                int p = atomicAdd(&cur[(int)(w & mask)], 1);
                lbuf[p] = (int)(w >> shift);
            }
        }
        __syncthreads();
        for (int j = threadIdx.x; j < nedge; j += 256)
            col[colbase + j] = lbuf[j];
    } else {  // statistically unreachable fallback (bucket > LDSBUF edges)
        for (int t = threadIdx.x; t < ntiles; t += 256) {
            const int* row = table + (size_t)t * TSTRIDE + b;
            int a = row[0], e2 = row[1];
            const uint* slab = bins + (size_t)t * 4096;
            for (int j = a; j < e2; ++j) {
                uint w = slab[j];
                int p = atomicAdd(&cur[(int)(w & mask)], 1);
                col[colbase + p] = (int)(w >> shift);
            }
        }
    }
}

// ---- 128B-row gather (one wave per node; r=lane>>3 row slot, c=lane&7 chunk).
// ends[node] = start of node+1 (pass deg+1); ends[node-1] = start of node.
// COMBINE=0: bf16 out at (ob_pitch, ob_off).
// COMBINE=1: outf = (x0 + x1 + mean)/3, x1 bf16 at (x1_pitch, x1_off).
// NOTE: outf may alias x1's buffer (same row, same wave) — data dependency
// (store value uses loaded x1) keeps this safe; no __restrict__ on those.
template <int COMBINE>
__global__ __launch_bounds__(256) void gather128(
        const ushort* __restrict__ feat,
        const int* __restrict__ ends,
        const int* __restrict__ col,
        const float* __restrict__ x0,
        const ushort* x1, int x1_pitch, int x1_off,
        float* outf,
        ushort* outb, int ob_pitch, int ob_off,
        int n) {
    int node = blockIdx.x * 4 + (threadIdx.x >> 6);
    if (node >= n) return;
    int lane = threadIdx.x & 63;
    int r = lane >> 3, c = lane & 7;
    int beg = ends[node - 1];
    int end = ends[node];
    const ushort* fbase = feat + c * 8;

    float acc[8];
    #pragma unroll
    for (int j = 0; j < 8; ++j) acc[j] = 0.0f;

    for (int e = beg; e < end; e += 16) {
        int i0 = e + r, i1 = e + 8 + r;
        bool ok0 = i0 < end, ok1 = i1 < end;
        int nb0 = col[ok0 ? i0 : beg];
        int nb1 = col[ok1 ? i1 : beg];
        uint4 v0 = *(const uint4*)(fbase + (size_t)nb0 * DIM);
        uint4 v1 = *(const uint4*)(fbase + (size_t)nb1 * DIM);
        if (ok0) {
            acc[0] += bf16_lo(v0.x); acc[1] += bf16_hi(v0.x);
            acc[2] += bf16_lo(v0.y); acc[3] += bf16_hi(v0.y);
            acc[4] += bf16_lo(v0.z); acc[5] += bf16_hi(v0.z);
            acc[6] += bf16_lo(v0.w); acc[7] += bf16_hi(v0.w);
        }
        if (ok1) {
            acc[0] += bf16_lo(v1.x); acc[1] += bf16_hi(v1.x);
            acc[2] += bf16_lo(v1.y); acc[3] += bf16_hi(v1.y);
            acc[4] += bf16_lo(v1.z); acc[5] += bf16_hi(v1.z);
            acc[6] += bf16_lo(v1.w); acc[7] += bf16_hi(v1.w);
        }
    }
    #pragma unroll
    for (int m = 8; m < 64; m <<= 1) {
        #pragma unroll
        for (int j = 0; j < 8; ++j) acc[j] += __shfl_xor(acc[j], m, 64);
    }
    if (r == 0) {
        int d = end - beg;
        float inv = (d > 0) ? 1.0f / (float)d : 0.0f;
        if (COMBINE) {
            size_t base = (size_t)node * DIM + c * 8;
            float4 xa = *(const float4*)(x0 + base);
            float4 xb = *(const float4*)(x0 + base + 4);
            uint4  xq = *(const uint4*)(x1 + (size_t)node * x1_pitch + x1_off + c * 8);
            float4 oa, ob;
            oa.x = (xa.x + bf16_lo(xq.x) + acc[0] * inv) * (1.0f / 3.0f);
            oa.y = (xa.y + bf16_hi(xq.x) + acc[1] * inv) * (1.0f / 3.0f);
            oa.z = (xa.z + bf16_lo(xq.y) + acc[2] * inv) * (1.0f / 3.0f);
            oa.w = (xa.w + bf16_hi(xq.y) + acc[3] * inv) * (1.0f / 3.0f);
            ob.x = (xb.x + bf16_lo(xq.z) + acc[4] * inv) * (1.0f / 3.0f);
            ob.y = (xb.y + bf16_hi(xq.z) + acc[5] * inv) * (1.0f / 3.0f);
            ob.z = (xb.z + bf16_lo(xq.w) + acc[6] * inv) * (1.0f / 3.0f);
            ob.w = (xb.w + bf16_hi(xq.w) + acc[7] * inv) * (1.0f / 3.0f);
            *(float4*)(outf + base)     = oa;
            *(float4*)(outf + base + 4) = ob;
        } else {
            uint4 o;
            o.x = f2b(acc[0] * inv) | (f2b(acc[1] * inv) << 16);
            o.y = f2b(acc[2] * inv) | (f2b(acc[3] * inv) << 16);
            o.z = f2b(acc[4] * inv) | (f2b(acc[5] * inv) << 16);
            o.w = f2b(acc[6] * inv) | (f2b(acc[7] * inv) << 16);
            *(uint4*)(outb + (size_t)node * ob_pitch + ob_off + c * 8) = o;
        }
    }
}

// ---- 256B-row fused item pass: feat = u01 (u0|u1 interleaved, pitch 128).
// Computes i1 = mean(u0-nbrs), i2 = mean(u1-nbrs) in ONE col walk.
// outf = (x0 + i1 + i2)/3 (f32), outb = bf16(i1) (dense pitch 64).
__global__ __launch_bounds__(256) void gather256_combine(
        const ushort* __restrict__ feat,
        const int* __restrict__ ends,
        const int* __restrict__ col,
        const float* __restrict__ x0,
        float* __restrict__ outf,
        ushort* __restrict__ outb,
        int n) {
    int node = blockIdx.x * 4 + (threadIdx.x >> 6);
    if (node >= n) return;
    int lane = threadIdx.x & 63;
    int c = lane & 15, r = lane >> 4;          // c: 16B chunk of 256B row
    int beg = ends[node - 1];
    int end = ends[node];
    const ushort* fbase = feat + c * 8;

    float acc[8];
    #pragma unroll
    for (int j = 0; j < 8; ++j) acc[j] = 0.0f;

    for (int e = beg; e < end; e += 8) {
        int i0 = e + r, i1 = e + 4 + r;
        bool ok0 = i0 < end, ok1 = i1 < end;
        int nb0 = col[ok0 ? i0 : beg];
        int nb1 = col[ok1 ? i1 : beg];
        uint4 v0 = *(const uint4*)(fbase + (size_t)nb0 * 128);
        uint4 v1 = *(const uint4*)(fbase + (size_t)nb1 * 128);
        if (ok0) {
            acc[0] += bf16_lo(v0.x); acc[1] += bf16_hi(v0.x);
            acc[2] += bf16_lo(v0.y); acc[3] += bf16_hi(v0.y);
            acc[4] += bf16_lo(v0.z); acc[5] += bf16_hi(v0.z);
            acc[6] += bf16_lo(v0.w); acc[7] += bf16_hi(v0.w);
        }
        if (ok1) {
            acc[0] += bf16_lo(v1.x); acc[1] += bf16_hi(v1.x);
            acc[2] += bf16_lo(v1.y); acc[3] += bf16_hi(v1.y);
            acc[4] += bf16_lo(v1.z); acc[5] += bf16_hi(v1.z);
            acc[6] += bf16_lo(v1.w); acc[7] += bf16_hi(v1.w);
        }
    }
    // fold the 4 r-slots (lane bits 4,5)
    #pragma unroll
    for (int m = 16; m < 64; m <<= 1) {
        #pragma unroll
        for (int j = 0; j < 8; ++j) acc[j] += __shfl_xor(acc[j], m, 64);
    }
    // partner exchange: lane c (<8, u0-part) pairs with lane c+8 (u1-part, same elems)
    float b8[8];
    #pragma unroll
    for (int j = 0; j < 8; ++j) b8[j] = __shfl_xor(acc[j], 8, 64);

    if (r == 0 && c < 8) {
        int d = end - beg;
        float inv = (d > 0) ? 1.0f / (float)d : 0.0f;
        size_t base = (size_t)node * DIM + c * 8;
        float4 xa = *(const float4*)(x0 + base);
        float4 xb = *(const float4*)(x0 + base + 4);
        float i1v[8];
        #pragma unroll
        for (int j = 0; j < 8; ++j) i1v[j] = acc[j] * inv;
        float4 oa, ob;
        oa.x = (xa.x + i1v[0] + b8[0] * inv) * (1.0f / 3.0f);
        oa.y = (xa.y + i1v[1] + b8[1] * inv) * (1.0f / 3.0f);
        oa.z = (xa.z + i1v[2] + b8[2] * inv) * (1.0f / 3.0f);
        oa.w = (xa.w + i1v[3] + b8[3] * inv) * (1.0f / 3.0f);
        ob.x = (xb.x + i1v[4] + b8[4] * inv) * (1.0f / 3.0f);
        ob.y = (xb.y + i1v[5] + b8[5] * inv) * (1.0f / 3.0f);
        ob.z = (xb.z + i1v[6] + b8[6] * inv) * (1.0f / 3.0f);
        ob.w = (xb.w + i1v[7] + b8[7] * inv) * (1.0f / 3.0f);
        *(float4*)(outf + base)     = oa;
        *(float4*)(outf + base + 4) = ob;
        uint4 q;
        q.x = f2b(i1v[0]) | (f2b(i1v[1]) << 16);
        q.y = f2b(i1v[2]) | (f2b(i1v[3]) << 16);
        q.z = f2b(i1v[4]) | (f2b(i1v[5]) << 16);
        q.w = f2b(i1v[6]) | (f2b(i1v[7]) << 16);
        *(uint4*)(outb + base) = q;
    }
}

extern "C" void kernel_launch(void* const* d_in, const int* in_sizes, int n_in,
                              void* d_out, int out_size, void* d_ws, size_t ws_size,
                              hipStream_t stream) {
    const float* u0  = (const float*)d_in[0];
    const float* i0  = (const float*)d_in[1];
    const int*   src = (const int*)d_in[2];
    const int*   dst = (const int*)d_in[3];

    const int n_users = in_sizes[0] / DIM;   // 200000
    const int n_items = in_sizes[1] / DIM;   // 100000
    const int E       = in_sizes[2];         // 3000000
    const int n_nodes = n_users + n_items;
    const int nu_pb   = (n_users + NBK - 1) / NBK;   // 782 (< 2^10: packing req)
    const int ni_pb   = (n_items + NBK - 1) / NBK;   // 391 (< 2^9:  packing req)

    const size_t u_elems = (size_t)n_users * DIM;
    const size_t i_elems = (size_t)n_items * DIM;

    // Workspace (~38 MB): deg[n_nodes+1] | bsum[1024] | col[2E] | ib[i_elems bf16]
    int* deg  = (int*)d_ws;
    int* bsum = deg + n_nodes + 1;
    int* col  = bsum + 1024;
    ushort* ib = (ushort*)(col + 2 * (size_t)E);  // i0 bf16, later i1 bf16

    // d_out: user region doubles as the per-tile offset table (3.1 MB) during
    // CSR build, then as u01 (u0|u1 interleaved bf16, 256B rows). item region
    // (out_i, 25.6 MB) doubles as the slab array (23.4 MB) — dead until
    // gather256_combine writes it.
    float* out_u = (float*)d_out;
    float* out_i = out_u + u_elems;
    ushort* u01  = (ushort*)d_out;         // exactly overlays out_u (51.2 MB)
    int*   table = (int*)d_out;
    uint*  bins  = (uint*)out_i;

    const int BLK = 256;
    const int nb = (n_nodes + SCAN_B - 1) / SCAN_B;
    const int ntiles = (E + BLK * TEPT - 1) / (BLK * TEPT);   // 1465

    // ---- CSR build: bin(+deg hist) -> node scan -> set_last -> fill ----
    hipMemsetAsync(deg, 0, (size_t)(n_nodes + 1) * sizeof(int), stream);
    bin_chunked<<<ntiles, BLK, 0, stream>>>(src, dst, deg, table, bins,
                                            E, n_users, nu_pb, ni_pb);
    scan1<<<nb, SCAN_B, 0, stream>>>(deg, bsum, n_nodes);
    scan2<<<1, SCAN_B, 0, stream>>>(bsum, nb);
    scan3<<<nb, SCAN_B, 0, stream>>>(deg, bsum, n_nodes);
    set_last<<<1, 64, 0, stream>>>(deg, n_nodes, 2 * E);
    fill_node<<<2 * NBK, BLK, 0, stream>>>(bins, table, deg, col,
                                           n_users, n_items, ntiles, nu_pb, ni_pb);
    // deg holds pristine exclusive starts; ends pointer = deg + 1 (+n_users).

    // ---- stage bf16 (table/bins regions are dead from here on) ----
    cvt_bf16_pitch<<<(int)((u_elems / 8 + BLK - 1) / BLK), BLK, 0, stream>>>(
        u0, u01, (int)(u_elems / 8), 128, 0);
    cvt_bf16_pitch<<<(int)((i_elems / 8 + BLK - 1) / BLK), BLK, 0, stream>>>(
        i0, ib, (int)(i_elems / 8), 64, 0);

    const int ug = (n_users + 3) / 4;
    const int ig = (n_items + 3) / 4;

    // ---- Pass A: u1 = mean(i0-nbrs) -> u01 odd halves (bf16) ----
    gather128<0><<<ug, BLK, 0, stream>>>(ib, deg + 1, col, nullptr,
                                         nullptr, 0, 0, nullptr,
                                         u01, 128, 64, n_users);

    // ---- Pass C: fused item pass: out_i = (i0 + i1 + i2)/3, ib <- bf16(i1) ----
    gather256_combine<<<ig, BLK, 0, stream>>>(u01, deg + n_users + 1, col,
                                              i0, out_i, ib, n_items);

    // ---- Pass D: out_u = (u0 + u1 + mean(i1-nbrs))/3 (u1 from u01 odd) ----
    gather128<1><<<ug, BLK, 0, stream>>>(ib, deg + 1, col, u0,
                                         u01, 128, 64, out_u,
                                         nullptr, 0, 0, n_users);
}

// Round 7
// 572.969 us; speedup vs baseline: 1.7601x; 1.3129x over previous
//
#include <hip/hip_runtime.h>

#define DIM 64
#define NBK 256       // node buckets per side (users / items)
#define TEPT 8        // edges per thread in bin_chunked (tile = 2048 edges)
#define TSTRIDE 528   // table row stride in ints (513 used, 64B-aligned rows)
#define LDSBUF 14336  // fill_node staged col entries (56 KB); mean 11719, +24 sigma

typedef unsigned int uint;
typedef unsigned short ushort;

// ---- bf16 helpers ----
__device__ __forceinline__ float bf16_lo(uint u) {
    union { uint u; float f; } c; c.u = u << 16; return c.f;
}
__device__ __forceinline__ float bf16_hi(uint u) {
    union { uint u; float f; } c; c.u = u & 0xffff0000u; return c.f;
}
__device__ __forceinline__ uint f2b(float f) {   // bf16 in low 16 bits (RNE)
    union { float f; uint u; } c; c.f = f;
    return (c.u + 0x7fffu + ((c.u >> 16) & 1u)) >> 16;
}

// f32 -> bf16, 8 elems/thread, output row pitch/offset in ushorts (rows of 64).
__global__ void cvt_bf16_pitch(const float* __restrict__ in, ushort* __restrict__ out,
                               int n8, int pitch, int off) {
    int k = blockIdx.x * blockDim.x + threadIdx.x;
    if (k >= n8) return;
    int row = k >> 3, g = k & 7;
    const float4* p = (const float4*)in + (size_t)k * 2;
    float4 a = p[0], b = p[1];
    uint4 o;
    o.x = f2b(a.x) | (f2b(a.y) << 16);
    o.y = f2b(a.z) | (f2b(a.w) << 16);
    o.z = f2b(b.x) | (f2b(b.y) << 16);
    o.w = f2b(b.z) | (f2b(b.w) << 16);
    *(uint4*)(out + (size_t)row * pitch + off + g * 8) = o;
}

// ---- CSR build, chunked-slab design, ZERO global atomics ----
// (6M global atomicAdds cost 32B/HBM-write each = 192 MB — measured r6.)
// One pass over the edge list. Per tile (2048 edges -> 4096 entries):
//  - LDS per-bucket counts (512 buckets: 256 user node-ranges + 256 item)
//  - LDS exclusive scan -> bucket-grouped layout inside the tile's OWN
//    contiguous 16 KB slab (zero write amplification, no global cursors)
//  - per-tile 513-int offset table row (coalesced)
// Entry words: user: (s % nu_pb) | t<<10 (782<2^10, t<2^17 -> 27b)
//              item: (t % ni_pb) | s<<9  (391<2^9,  s<2^18 -> 27b)
__global__ __launch_bounds__(256) void bin_chunked(
        const int* __restrict__ src, const int* __restrict__ dst,
        int* __restrict__ table, uint* __restrict__ bins,
        int E, int n_users, int nu_pb, int ni_pb) {
    __shared__ int cnt[2 * NBK];
    __shared__ int lbase[2 * NBK + 1];
    __shared__ uint ord[4096];
    for (int i = threadIdx.x; i < 2 * NBK; i += 256) cnt[i] = 0;
    __syncthreads();
    int t0 = blockIdx.x * (256 * TEPT) + threadIdx.x;
    uint st[2 * TEPT];   // packed (bucket<<12 | local offset), static idx only
    #pragma unroll
    for (int k = 0; k < TEPT; ++k) {
        int e = t0 + k * 256;
        if (e < E) {
            int s = src[e], t = dst[e];
            int bu = s / nu_pb;
            int bi = t / ni_pb;
            int ou = atomicAdd(&cnt[bu], 1);
            int oi = atomicAdd(&cnt[NBK + bi], 1);
            st[2 * k]     = ((uint)bu << 12) | (uint)ou;
            st[2 * k + 1] = ((uint)(NBK + bi) << 12) | (uint)oi;
        }
    }
    __syncthreads();
    if (threadIdx.x == 0) {
        int run = 0;
        for (int i = 0; i < 2 * NBK; ++i) { lbase[i] = run; run += cnt[i]; }
        lbase[2 * NBK] = run;
    }
    __syncthreads();
    int* trow = table + (size_t)blockIdx.x * TSTRIDE;
    for (int i = threadIdx.x; i <= 2 * NBK; i += 256) trow[i] = lbase[i];
    // phase 2: re-read edges (L1-warm), place into bucket-grouped LDS
    #pragma unroll
    for (int k = 0; k < TEPT; ++k) {
        int e = t0 + k * 256;
        if (e < E) {
            int s = src[e], t = dst[e];
            uint su = st[2 * k], si = st[2 * k + 1];
            int bu = (int)(su >> 12);
            int bi = (int)(si >> 12);
            uint wu = (uint)(s - bu * nu_pb) | ((uint)t << 10);
            uint wi = (uint)(t - (bi - NBK) * ni_pb) | ((uint)s << 9);
            ord[lbase[bu] + (int)(su & 4095u)] = wu;
            ord[lbase[bi] + (int)(si & 4095u)] = wi;
        }
    }
    __syncthreads();
    int tot = lbase[2 * NBK];
    uint* slab = bins + (size_t)blockIdx.x * 4096;
    for (int j = threadIdx.x; j < tot; j += 256)
        slab[j] = ord[j];
}

// Per-bucket edge totals from the per-tile table (L3-resident, 3 MB).
__global__ __launch_bounds__(256) void bucket_sums(
        const int* __restrict__ table, int* __restrict__ btot, int ntiles) {
    int b = blockIdx.x;   // 0..511
    int s = 0;
    for (int t = threadIdx.x; t < ntiles; t += 256) {
        const int* row = table + (size_t)t * TSTRIDE + b;
        s += row[1] - row[0];
    }
    #pragma unroll
    for (int m = 1; m < 64; m <<= 1) s += __shfl_xor(s, m, 64);
    __shared__ int ws[4];
    int lane = threadIdx.x & 63, wid = threadIdx.x >> 6;
    if (lane == 0) ws[wid] = s;
    __syncthreads();
    if (threadIdx.x == 0) btot[b] = ws[0] + ws[1] + ws[2] + ws[3];
}

// Exclusive scan of the 512 bucket totals -> bucket col bases. Also seals
// deg[n_nodes] = 2E.
__global__ void scan512(const int* __restrict__ btot, int* __restrict__ bstart,
                        int* __restrict__ deg, int n_nodes, int total) {
    __shared__ int ws[8];
    int lane = threadIdx.x & 63, wid = threadIdx.x >> 6;
    int v = btot[threadIdx.x];
    int incl = v;
    #pragma unroll
    for (int off = 1; off < 64; off <<= 1) {
        int t = __shfl_up(incl, off, 64);
        if (lane >= off) incl += t;
    }
    if (lane == 63) ws[wid] = incl;
    __syncthreads();
    int woff = 0;
    for (int w = 0; w < wid; ++w) woff += ws[w];
    bstart[threadIdx.x] = woff + incl - v;
    if ((int)threadIdx.x == 511) {
        bstart[512] = total;
        deg[n_nodes] = total;
    }
}

// One block per bucket (512 blocks), exclusive node-range ownership.
// Pass 1: per-node degree histogram via LDS atomics over the bucket's slab
// slices. In-LDS chunked block scan -> per-node exclusive prefix; deg written
// DENSE (replaces the 300K-node global scan chain AND the 6M global atomics).
// Pass 2: placement via LDS cursor atomics into a staged 56 KB col segment,
// written out dense -> zero write amplification.
__global__ __launch_bounds__(256) void fill_node(
        const uint* __restrict__ bins, const int* __restrict__ table,
        const int* __restrict__ bstart, int* __restrict__ deg,
        int* __restrict__ col,
        int n_users, int n_items, int ntiles, int nu_pb, int ni_pb) {
    __shared__ int cur[800];
    __shared__ int ws[4];
    __shared__ int lbuf[LDSBUF];
    int b = blockIdx.x;
    bool user = b < NBK;
    int bb = user ? b : b - NBK;
    int npb = user ? nu_pb : ni_pb;
    int ncnt = user ? n_users : n_items;
    int node0 = bb * npb;
    int nn = min(npb, ncnt - node0);
    if (nn <= 0) return;
    int idx0 = (user ? 0 : n_users) + node0;
    int colbase = bstart[b];
    int nedge = bstart[b + 1] - colbase;
    uint mask = user ? 1023u : 511u;
    int shift = user ? 10 : 9;

    for (int i = threadIdx.x; i < nn; i += 256) cur[i] = 0;
    __syncthreads();
    // pass 1: per-node histogram (LDS atomics only)
    for (int t = threadIdx.x; t < ntiles; t += 256) {
        const int* row = table + (size_t)t * TSTRIDE + b;
        int a = row[0], e2 = row[1];
        const uint* slab = bins + (size_t)t * 4096;
        for (int j = a; j < e2; ++j)
            atomicAdd(&cur[(int)(slab[j] & mask)], 1);
    }
    __syncthreads();
    // chunked exclusive scan of cur[0..nn): thread chunk sums -> wave scan
    int CH = (nn + 255) >> 8;
    int c0 = threadIdx.x * CH;
    int s = 0;
    for (int i = 0; i < CH; ++i) {
        int idx = c0 + i;
        if (idx < nn) s += cur[idx];
    }
    int lane = threadIdx.x & 63, wid = threadIdx.x >> 6;
    int incl = s;
    #pragma unroll
    for (int off = 1; off < 64; off <<= 1) {
        int t = __shfl_up(incl, off, 64);
        if (lane >= off) incl += t;
    }
    if (lane == 63) ws[wid] = incl;
    __syncthreads();
    int woff = 0;
    for (int w = 0; w < wid; ++w) woff += ws[w];
    int running = woff + incl - s;   // exclusive prefix of this thread's chunk
    for (int i = 0; i < CH; ++i) {
        int idx = c0 + i;
        if (idx < nn) {
            int c = cur[idx];
            cur[idx] = running;                  // local cursor start
            deg[idx0 + idx] = colbase + running; // dense deg write
            running += c;
        }
    }
    __syncthreads();
    // pass 2: placement
    if (nedge <= LDSBUF) {
        for (int t = threadIdx.x; t < ntiles; t += 256) {
            const int* row = table + (size_t)t * TSTRIDE + b;
            int a = row[0], e2 = row[1];
            const uint* slab = bins + (size_t)t * 4096;
            for (int j = a; j < e2; ++j) {
                uint w = slab[j];
                int p = atomicAdd(&cur[(int)(w & mask)], 1);
                lbuf[p] = (int)(w >> shift);
            }
        }
        __syncthreads();
        for (int j = threadIdx.x; j < nedge; j += 256)
            col[colbase + j] = lbuf[j];
    } else {  // statistically unreachable fallback (bucket > LDSBUF edges)
        for (int t = threadIdx.x; t < ntiles; t += 256) {
            const int* row = table + (size_t)t * TSTRIDE + b;
            int a = row[0], e2 = row[1];
            const uint* slab = bins + (size_t)t * 4096;
            for (int j = a; j < e2; ++j) {
                uint w = slab[j];
                int p = atomicAdd(&cur[(int)(w & mask)], 1);
                col[colbase + p] = (int)(w >> shift);
            }
        }
    }
}

// ---- 128B-row gather (one wave per node; r=lane>>3 row slot, c=lane&7 chunk).
// ends[node] = start of node+1 (pass deg+1); ends[node-1] = start of node.
// COMBINE=0: bf16 out at (ob_pitch, ob_off).
// COMBINE=1: outf = (x0 + x1 + mean)/3, x1 bf16 at (x1_pitch, x1_off).
// NOTE: outf may alias x1's buffer (same row, same wave) — data dependency
// (store value uses loaded x1) keeps this safe; no __restrict__ on those.
template <int COMBINE>
__global__ __launch_bounds__(256) void gather128(
        const ushort* __restrict__ feat,
        const int* __restrict__ ends,
        const int* __restrict__ col,
        const float* __restrict__ x0,
        const ushort* x1, int x1_pitch, int x1_off,
        float* outf,
        ushort* outb, int ob_pitch, int ob_off,
        int n) {
    int node = blockIdx.x * 4 + (threadIdx.x >> 6);
    if (node >= n) return;
    int lane = threadIdx.x & 63;
    int r = lane >> 3, c = lane & 7;
    int beg = ends[node - 1];
    int end = ends[node];
    const ushort* fbase = feat + c * 8;

    float acc[8];
    #pragma unroll
    for (int j = 0; j < 8; ++j) acc[j] = 0.0f;

    for (int e = beg; e < end; e += 16) {
        int i0 = e + r, i1 = e + 8 + r;
        bool ok0 = i0 < end, ok1 = i1 < end;
        int nb0 = col[ok0 ? i0 : beg];
        int nb1 = col[ok1 ? i1 : beg];
        uint4 v0 = *(const uint4*)(fbase + (size_t)nb0 * DIM);
        uint4 v1 = *(const uint4*)(fbase + (size_t)nb1 * DIM);
        if (ok0) {
            acc[0] += bf16_lo(v0.x); acc[1] += bf16_hi(v0.x);
            acc[2] += bf16_lo(v0.y); acc[3] += bf16_hi(v0.y);
            acc[4] += bf16_lo(v0.z); acc[5] += bf16_hi(v0.z);
            acc[6] += bf16_lo(v0.w); acc[7] += bf16_hi(v0.w);
        }
        if (ok1) {
            acc[0] += bf16_lo(v1.x); acc[1] += bf16_hi(v1.x);
            acc[2] += bf16_lo(v1.y); acc[3] += bf16_hi(v1.y);
            acc[4] += bf16_lo(v1.z); acc[5] += bf16_hi(v1.z);
            acc[6] += bf16_lo(v1.w); acc[7] += bf16_hi(v1.w);
        }
    }
    #pragma unroll
    for (int m = 8; m < 64; m <<= 1) {
        #pragma unroll
        for (int j = 0; j < 8; ++j) acc[j] += __shfl_xor(acc[j], m, 64);
    }
    if (r == 0) {
        int d = end - beg;
        float inv = (d > 0) ? 1.0f / (float)d : 0.0f;
        if (COMBINE) {
            size_t base = (size_t)node * DIM + c * 8;
            float4 xa = *(const float4*)(x0 + base);
            float4 xb = *(const float4*)(x0 + base + 4);
            uint4  xq = *(const uint4*)(x1 + (size_t)node * x1_pitch + x1_off + c * 8);
            float4 oa, ob;
            oa.x = (xa.x + bf16_lo(xq.x) + acc[0] * inv) * (1.0f / 3.0f);
            oa.y = (xa.y + bf16_hi(xq.x) + acc[1] * inv) * (1.0f / 3.0f);
            oa.z = (xa.z + bf16_lo(xq.y) + acc[2] * inv) * (1.0f / 3.0f);
            oa.w = (xa.w + bf16_hi(xq.y) + acc[3] * inv) * (1.0f / 3.0f);
            ob.x = (xb.x + bf16_lo(xq.z) + acc[4] * inv) * (1.0f / 3.0f);
            ob.y = (xb.y + bf16_hi(xq.z) + acc[5] * inv) * (1.0f / 3.0f);
            ob.z = (xb.z + bf16_lo(xq.w) + acc[6] * inv) * (1.0f / 3.0f);
            ob.w = (xb.w + bf16_hi(xq.w) + acc[7] * inv) * (1.0f / 3.0f);
            *(float4*)(outf + base)     = oa;
            *(float4*)(outf + base + 4) = ob;
        } else {
            uint4 o;
            o.x = f2b(acc[0] * inv) | (f2b(acc[1] * inv) << 16);
            o.y = f2b(acc[2] * inv) | (f2b(acc[3] * inv) << 16);
            o.z = f2b(acc[4] * inv) | (f2b(acc[5] * inv) << 16);
            o.w = f2b(acc[6] * inv) | (f2b(acc[7] * inv) << 16);
            *(uint4*)(outb + (size_t)node * ob_pitch + ob_off + c * 8) = o;
        }
    }
}

// ---- 256B-row fused item pass: feat = u01 (u0|u1 interleaved, pitch 128).
// Computes i1 = mean(u0-nbrs), i2 = mean(u1-nbrs) in ONE col walk.
// outf = (x0 + i1 + i2)/3 (f32), outb = bf16(i1) (dense pitch 64).
__global__ __launch_bounds__(256) void gather256_combine(
        const ushort* __restrict__ feat,
        const int* __restrict__ ends,
        const int* __restrict__ col,
        const float* __restrict__ x0,
        float* __restrict__ outf,
        ushort* __restrict__ outb,
        int n) {
    int node = blockIdx.x * 4 + (threadIdx.x >> 6);
    if (node >= n) return;
    int lane = threadIdx.x & 63;
    int c = lane & 15, r = lane >> 4;          // c: 16B chunk of 256B row
    int beg = ends[node - 1];
    int end = ends[node];
    const ushort* fbase = feat + c * 8;

    float acc[8];
    #pragma unroll
    for (int j = 0; j < 8; ++j) acc[j] = 0.0f;

    for (int e = beg; e < end; e += 8) {
        int i0 = e + r, i1 = e + 4 + r;
        bool ok0 = i0 < end, ok1 = i1 < end;
        int nb0 = col[ok0 ? i0 : beg];
        int nb1 = col[ok1 ? i1 : beg];
        uint4 v0 = *(const uint4*)(fbase + (size_t)nb0 * 128);
        uint4 v1 = *(const uint4*)(fbase + (size_t)nb1 * 128);
        if (ok0) {
            acc[0] += bf16_lo(v0.x); acc[1] += bf16_hi(v0.x);
            acc[2] += bf16_lo(v0.y); acc[3] += bf16_hi(v0.y);
            acc[4] += bf16_lo(v0.z); acc[5] += bf16_hi(v0.z);
            acc[6] += bf16_lo(v0.w); acc[7] += bf16_hi(v0.w);
        }
        if (ok1) {
            acc[0] += bf16_lo(v1.x); acc[1] += bf16_hi(v1.x);
            acc[2] += bf16_lo(v1.y); acc[3] += bf16_hi(v1.y);
            acc[4] += bf16_lo(v1.z); acc[5] += bf16_hi(v1.z);
            acc[6] += bf16_lo(v1.w); acc[7] += bf16_hi(v1.w);
        }
    }
    // fold the 4 r-slots (lane bits 4,5)
    #pragma unroll
    for (int m = 16; m < 64; m <<= 1) {
        #pragma unroll
        for (int j = 0; j < 8; ++j) acc[j] += __shfl_xor(acc[j], m, 64);
    }
    // partner exchange: lane c (<8, u0-part) pairs with lane c+8 (u1-part, same elems)
    float b8[8];
    #pragma unroll
    for (int j = 0; j < 8; ++j) b8[j] = __shfl_xor(acc[j], 8, 64);

    if (r == 0 && c < 8) {
        int d = end - beg;
        float inv = (d > 0) ? 1.0f / (float)d : 0.0f;
        size_t base = (size_t)node * DIM + c * 8;
        float4 xa = *(const float4*)(x0 + base);
        float4 xb = *(const float4*)(x0 + base + 4);
        float i1v[8];
        #pragma unroll
        for (int j = 0; j < 8; ++j) i1v[j] = acc[j] * inv;
        float4 oa, ob;
        oa.x = (xa.x + i1v[0] + b8[0] * inv) * (1.0f / 3.0f);
        oa.y = (xa.y + i1v[1] + b8[1] * inv) * (1.0f / 3.0f);
        oa.z = (xa.z + i1v[2] + b8[2] * inv) * (1.0f / 3.0f);
        oa.w = (xa.w + i1v[3] + b8[3] * inv) * (1.0f / 3.0f);
        ob.x = (xb.x + i1v[4] + b8[4] * inv) * (1.0f / 3.0f);
        ob.y = (xb.y + i1v[5] + b8[5] * inv) * (1.0f / 3.0f);
        ob.z = (xb.z + i1v[6] + b8[6] * inv) * (1.0f / 3.0f);
        ob.w = (xb.w + i1v[7] + b8[7] * inv) * (1.0f / 3.0f);
        *(float4*)(outf + base)     = oa;
        *(float4*)(outf + base + 4) = ob;
        uint4 q;
        q.x = f2b(i1v[0]) | (f2b(i1v[1]) << 16);
        q.y = f2b(i1v[2]) | (f2b(i1v[3]) << 16);
        q.z = f2b(i1v[4]) | (f2b(i1v[5]) << 16);
        q.w = f2b(i1v[6]) | (f2b(i1v[7]) << 16);
        *(uint4*)(outb + base) = q;
    }
}

extern "C" void kernel_launch(void* const* d_in, const int* in_sizes, int n_in,
                              void* d_out, int out_size, void* d_ws, size_t ws_size,
                              hipStream_t stream) {
    const float* u0  = (const float*)d_in[0];
    const float* i0  = (const float*)d_in[1];
    const int*   src = (const int*)d_in[2];
    const int*   dst = (const int*)d_in[3];

    const int n_users = in_sizes[0] / DIM;   // 200000
    const int n_items = in_sizes[1] / DIM;   // 100000
    const int E       = in_sizes[2];         // 3000000
    const int n_nodes = n_users + n_items;
    const int nu_pb   = (n_users + NBK - 1) / NBK;   // 782 (< 2^10: packing req)
    const int ni_pb   = (n_items + NBK - 1) / NBK;   // 391 (< 2^9:  packing req)

    const size_t u_elems = (size_t)n_users * DIM;
    const size_t i_elems = (size_t)n_items * DIM;

    // Workspace (~38 MB):
    //   deg[n_nodes+1] | btot[512] | bstart[513+pad] | col[2E] | ib[i_elems bf16]
    int* deg    = (int*)d_ws;
    int* btot   = deg + n_nodes + 1;
    int* bstart = btot + 512;
    int* col    = bstart + 516;
    ushort* ib  = (ushort*)(col + 2 * (size_t)E);  // i0 bf16, later i1 bf16

    // d_out: user region doubles as the per-tile offset table (3.1 MB) during
    // CSR build, then as u01 (u0|u1 interleaved bf16, 256B rows). item region
    // (out_i, 25.6 MB) doubles as the slab array (23.4 MB) — dead until
    // gather256_combine writes it.
    float* out_u = (float*)d_out;
    float* out_i = out_u + u_elems;
    ushort* u01  = (ushort*)d_out;         // exactly overlays out_u (51.2 MB)
    int*   table = (int*)d_out;
    uint*  bins  = (uint*)out_i;

    const int BLK = 256;
    const int ntiles = (E + BLK * TEPT - 1) / (BLK * TEPT);   // 1465

    // ---- CSR build: bin -> bucket sums -> bucket scan -> fill(deg+col) ----
    bin_chunked<<<ntiles, BLK, 0, stream>>>(src, dst, table, bins,
                                            E, n_users, nu_pb, ni_pb);
    bucket_sums<<<2 * NBK, BLK, 0, stream>>>(table, btot, ntiles);
    scan512<<<1, 512, 0, stream>>>(btot, bstart, deg, n_nodes, 2 * E);
    fill_node<<<2 * NBK, BLK, 0, stream>>>(bins, table, bstart, deg, col,
                                           n_users, n_items, ntiles, nu_pb, ni_pb);
    // deg holds exclusive starts (users then items), deg[n_nodes] = 2E.

    // ---- stage bf16 (table/bins regions are dead from here on) ----
    cvt_bf16_pitch<<<(int)((u_elems / 8 + BLK - 1) / BLK), BLK, 0, stream>>>(
        u0, u01, (int)(u_elems / 8), 128, 0);
    cvt_bf16_pitch<<<(int)((i_elems / 8 + BLK - 1) / BLK), BLK, 0, stream>>>(
        i0, ib, (int)(i_elems / 8), 64, 0);

    const int ug = (n_users + 3) / 4;
    const int ig = (n_items + 3) / 4;

    // ---- Pass A: u1 = mean(i0-nbrs) -> u01 odd halves (bf16) ----
    gather128<0><<<ug, BLK, 0, stream>>>(ib, deg + 1, col, nullptr,
                                         nullptr, 0, 0, nullptr,
                                         u01, 128, 64, n_users);

    // ---- Pass C: fused item pass: out_i = (i0 + i1 + i2)/3, ib <- bf16(i1) ----
    gather256_combine<<<ig, BLK, 0, stream>>>(u01, deg + n_users + 1, col,
                                              i0, out_i, ib, n_items);

    // ---- Pass D: out_u = (u0 + u1 + mean(i1-nbrs))/3 (u1 from u01 odd) ----
    gather128<1><<<ug, BLK, 0, stream>>>(ib, deg + 1, col, u0,
                                         u01, 128, 64, out_u,
                                         nullptr, 0, 0, n_users);
}